// Round 6
// baseline (2056.588 us; speedup 1.0000x reference)
//
#include <hip/hip_runtime.h>
#include <hip/hip_cooperative_groups.h>

namespace cg = cooperative_groups;

// ---------------------------------------------------------------------------
// Nystrom attention, fp32. b=2,h=8,n=8192,d=64, m=256 landmarks, conv33.
// Round 13: entire Moore-Penrose chain (25 GEMM steps) fused into ONE
// cooperative kernel with grid.sync() between steps — kills ~24 x ~15us
// launch/drain overhead. Tile body is byte-identical to verified
// k_bmm_planes. Everything else unchanged from round 12 (passed, 632us).
// ---------------------------------------------------------------------------

#define N_SEQ 8192
#define NBH   16
#define MLAND 256
#define DHEAD 64
#define NSPLIT3 8
#define MM_E  (NBH * MLAND * MLAND)   // 1048576 elements per plane
#define LM_E  (NBH * MLAND * DHEAD)   // 262144

typedef __attribute__((ext_vector_type(8))) short bfrag;
typedef __attribute__((ext_vector_type(8))) _Float16 hfrag;
typedef __attribute__((ext_vector_type(4))) float f32x4;

__device__ __forceinline__ void fma8(float (&o)[8], float p, const float4& a, const float4& b) {
    o[0] += p * a.x; o[1] += p * a.y; o[2] += p * a.z; o[3] += p * a.w;
    o[4] += p * b.x; o[5] += p * b.y; o[6] += p * b.z; o[7] += p * b.w;
}

__device__ __forceinline__ float bf2f(unsigned short h) {
    return __uint_as_float(((unsigned)h) << 16);
}

// truncation hi/lo split (bf16): hi = top 16 bits, lo = bf16(v - hi).
__device__ __forceinline__ void splitbf(float v, unsigned short& h, unsigned short& l) {
    unsigned bits = __float_as_uint(v);
    h = (unsigned short)(bits >> 16);
    float r = v - __uint_as_float(bits & 0xffff0000u);
    l = (unsigned short)(__float_as_uint(r) >> 16);
}

// fp16 hi/lo split: ~22 mantissa bits total. h = rn(v), l = rn(v - h).
__device__ __forceinline__ void splith(float v, unsigned short& h, unsigned short& l) {
    _Float16 hf = (_Float16)v;
    _Float16 lf = (_Float16)(v - (float)hf);
    h = __builtin_bit_cast(unsigned short, hf);
    l = __builtin_bit_cast(unsigned short, lf);
}

// read 16 consecutive floats, write hi/lo ushorts u32-packed (bf16 version)
__device__ __forceinline__ void stage16(const float* __restrict__ src,
                                        unsigned short* dh, unsigned short* dl) {
    unsigned* ph = (unsigned*)dh;
    unsigned* pl = (unsigned*)dl;
    #pragma unroll
    for (int o = 0; o < 16; o += 4) {
        float4 a = *(const float4*)(src + o);
        float vv[4] = {a.x, a.y, a.z, a.w};
        unsigned short h[4], l[4];
        #pragma unroll
        for (int u = 0; u < 4; ++u) splitbf(vv[u], h[u], l[u]);
        ph[o / 2]     = (unsigned)h[0] | ((unsigned)h[1] << 16);
        ph[o / 2 + 1] = (unsigned)h[2] | ((unsigned)h[3] << 16);
        pl[o / 2]     = (unsigned)l[0] | ((unsigned)l[1] << 16);
        pl[o / 2 + 1] = (unsigned)l[2] | ((unsigned)l[3] << 16);
    }
}

// fp16 version of stage16
__device__ __forceinline__ void stageh16(const float* __restrict__ src,
                                         unsigned short* dh, unsigned short* dl) {
    unsigned* ph = (unsigned*)dh;
    unsigned* pl = (unsigned*)dl;
    #pragma unroll
    for (int o = 0; o < 16; o += 4) {
        float4 a = *(const float4*)(src + o);
        float vv[4] = {a.x, a.y, a.z, a.w};
        unsigned short h[4], l[4];
        #pragma unroll
        for (int u = 0; u < 4; ++u) splith(vv[u], h[u], l[u]);
        ph[o / 2]     = (unsigned)h[0] | ((unsigned)h[1] << 16);
        ph[o / 2 + 1] = (unsigned)h[2] | ((unsigned)h[3] << 16);
        pl[o / 2]     = (unsigned)l[0] | ((unsigned)l[1] << 16);
        pl[o / 2 + 1] = (unsigned)l[2] | ((unsigned)l[3] << 16);
    }
}

// ---------------------------------------------------------------------------
// 1) landmark means
// ---------------------------------------------------------------------------
__global__ __launch_bounds__(64) void k_landmarks(
    const float* __restrict__ q, const float* __restrict__ k,
    float* __restrict__ ql, float* __restrict__ kl)
{
    int mi = blockIdx.x & 255;
    int bh = blockIdx.x >> 8;
    const float* src = blockIdx.y ? k : q;
    float*       dst = blockIdx.y ? kl : ql;
    int t = threadIdx.x;
    const float* s = src + ((size_t)bh * N_SEQ + (size_t)mi * 32) * DHEAD;
    float acc = 0.f;
    #pragma unroll
    for (int j = 0; j < 32; ++j) acc += s[j * DHEAD + t];
    dst[((size_t)bh * MLAND + mi) * DHEAD + t] = acc * (1.f / 32.f);
}

// ---------------------------------------------------------------------------
// 2) attn2 = softmax(ql @ kl^T) rowwise -> split bf16 planes (xh|xl)
// ---------------------------------------------------------------------------
__global__ __launch_bounds__(256) void k_sim2_softmax(
    const float* __restrict__ ql, const float* __restrict__ kl,
    unsigned short* __restrict__ xs)
{
    unsigned short* xh = xs;
    unsigned short* xl = xs + MM_E;
    int bh = blockIdx.x >> 8;
    int i  = blockIdx.x & 255;
    int t  = threadIdx.x;
    __shared__ float qrow[DHEAD];
    __shared__ float wred[8];
    if (t < DHEAD) qrow[t] = ql[((size_t)bh * MLAND + i) * DHEAD + t];
    __syncthreads();
    const float* krow = kl + ((size_t)bh * MLAND + t) * DHEAD;
    float s = 0.f;
    #pragma unroll
    for (int kk = 0; kk < DHEAD; kk += 4) {
        float4 k4 = *(const float4*)(krow + kk);
        s += qrow[kk] * k4.x + qrow[kk + 1] * k4.y + qrow[kk + 2] * k4.z + qrow[kk + 3] * k4.w;
    }
    float m = s;
    #pragma unroll
    for (int o = 32; o > 0; o >>= 1) m = fmaxf(m, __shfl_xor(m, o, 64));
    int wave = t >> 6, lane = t & 63;
    if (lane == 0) wred[wave] = m;
    __syncthreads();
    float bm = fmaxf(fmaxf(wred[0], wred[1]), fmaxf(wred[2], wred[3]));
    float e = __expf(s - bm);
    float sum = e;
    #pragma unroll
    for (int o = 32; o > 0; o >>= 1) sum += __shfl_xor(sum, o, 64);
    if (lane == 0) wred[4 + wave] = sum;
    __syncthreads();
    float bs = wred[4] + wred[5] + wred[6] + wred[7];
    float val = e / bs;
    unsigned short h, l;
    splitbf(val, h, l);
    size_t idx = ((size_t)bh * MLAND + i) * MLAND + t;
    xh[idx] = h;
    xl[idx] = l;
}

// ---------------------------------------------------------------------------
// 3a) global max of row-sums and col-sums of attn2 (from planes)
// ---------------------------------------------------------------------------
__global__ __launch_bounds__(256) void k_scale_reduce(
    const unsigned short* __restrict__ xs, float* __restrict__ scl)
{
    const unsigned short* xh = xs;
    const unsigned short* xl = xs + MM_E;
    int bh = blockIdx.x, t = threadIdx.x;
    size_t b = (size_t)bh * MLAND * MLAND;
    float colsum = 0.f, rowsum = 0.f;
    for (int i = 0; i < MLAND; ++i) {
        size_t idx = b + (size_t)i * MLAND + t;
        colsum += bf2f(xh[idx]) + bf2f(xl[idx]);
    }
    for (int j = 0; j < MLAND; ++j) {
        size_t idx = b + (size_t)t * MLAND + j;
        rowsum += bf2f(xh[idx]) + bf2f(xl[idx]);
    }
    __shared__ float red[256];
    red[t] = rowsum;
    __syncthreads();
    for (int o = 128; o > 0; o >>= 1) {
        if (t < o) red[t] = fmaxf(red[t], red[t + o]);
        __syncthreads();
    }
    if (t == 0) atomicMax((unsigned int*)&scl[0], __float_as_uint(red[0]));
    __syncthreads();
    red[t] = colsum;
    __syncthreads();
    for (int o = 128; o > 0; o >>= 1) {
        if (t < o) red[t] = fmaxf(red[t], red[t + o]);
        __syncthreads();
    }
    if (t == 0) atomicMax((unsigned int*)&scl[1], __float_as_uint(red[0]));
}

// ---------------------------------------------------------------------------
// 3b) z0 = attn2^T / (scl[0]*scl[1])  (planes -> planes)
// ---------------------------------------------------------------------------
__global__ __launch_bounds__(256) void k_zinit(
    const unsigned short* __restrict__ xs, unsigned short* __restrict__ zs,
    const float* __restrict__ scl)
{
    const unsigned short* xh = xs;
    const unsigned short* xl = xs + MM_E;
    unsigned short* zh = zs;
    unsigned short* zl = zs + MM_E;
    __shared__ float tile[32][33];
    int bh = blockIdx.z;
    int i0 = blockIdx.y * 32, j0 = blockIdx.x * 32;
    int t = threadIdx.x;
    int lx = t & 31, ly = t >> 5;
    size_t b = (size_t)bh * MLAND * MLAND;
    #pragma unroll
    for (int p = 0; p < 4; ++p) {
        size_t idx = b + (size_t)(i0 + ly + 8 * p) * MLAND + j0 + lx;
        tile[ly + 8 * p][lx] = bf2f(xh[idx]) + bf2f(xl[idx]);
    }
    __syncthreads();
    float inv = 1.0f / (scl[0] * scl[1]);
    #pragma unroll
    for (int p = 0; p < 4; ++p) {
        float val = tile[lx][ly + 8 * p] * inv;
        unsigned short h, l;
        splitbf(val, h, l);
        size_t idx = b + (size_t)(j0 + ly + 8 * p) * MLAND + i0 + lx;
        zh[idx] = h;
        zl[idx] = l;
    }
}

// ---------------------------------------------------------------------------
// 4) 64x64 tile of C = outscale * (A @ (diag*I + bscale*B)); planes in/out.
//    Byte-identical body to the verified k_bmm_planes (round 12).
// ---------------------------------------------------------------------------
__device__ __forceinline__ void bmm_tile(
    unsigned short* sm,
    const unsigned short* Ahp, const unsigned short* Alp,
    const unsigned short* Bhp, const unsigned short* Blp,
    unsigned short* Chp, unsigned short* Clp, float* Cf,
    int N, float diag, unsigned sflip, float outscale,
    int bh, int m0, int n0, int t)
{
    unsigned short* Ah = sm;
    unsigned short* Al = sm + 64 * 72;
    unsigned short* Bh = sm + 2 * 64 * 72;
    unsigned short* Bl = sm + 3 * 64 * 72;

    const size_t abase = (size_t)bh * 65536;
    const size_t bbase = (size_t)bh * 256 * N;
    int wave = t >> 6, lane = t & 63;
    int l15 = lane & 15, quad = lane >> 4;

    f32x4 acc[4] = {};

    for (int kc = 0; kc < 256; kc += 64) {
        __syncthreads();
        {   // stage A rows natural [m][k]: straight 32B copies per plane
            int m = t & 63, ks = (t >> 6) * 16;
            size_t off = abase + (size_t)(m0 + m) * 256 + kc + ks;
            *(uint4*)&Ah[m * 72 + ks]     = *(const uint4*)&Ahp[off];
            *(uint4*)&Ah[m * 72 + ks + 8] = *(const uint4*)&Ahp[off + 8];
            *(uint4*)&Al[m * 72 + ks]     = *(const uint4*)&Alp[off];
            *(uint4*)&Al[m * 72 + ks + 8] = *(const uint4*)&Alp[off + 8];
        }
        {   // stage B transposed [n][k]: vector load, sign-flip, scatter
            int kk = t & 63, ns = (t >> 6) * 16;
            int gk = kc + kk;
            size_t off = bbase + (size_t)gk * N + n0 + ns;
            unsigned short hb[16], lb[16];
            *(uint4*)&hb[0] = *(const uint4*)&Bhp[off];
            *(uint4*)&hb[8] = *(const uint4*)&Bhp[off + 8];
            *(uint4*)&lb[0] = *(const uint4*)&Blp[off];
            *(uint4*)&lb[8] = *(const uint4*)&Blp[off + 8];
            #pragma unroll
            for (int u = 0; u < 16; ++u) {
                unsigned short h = hb[u] ^ sflip;
                unsigned short l = lb[u] ^ sflip;
                if (diag != 0.f && gk == n0 + ns + u) {
                    float val = diag + bf2f(h) + bf2f(l);
                    splitbf(val, h, l);
                }
                Bh[(ns + u) * 72 + kk] = h;
                Bl[(ns + u) * 72 + kk] = l;
            }
        }
        __syncthreads();

        #pragma unroll
        for (int k0 = 0; k0 < 64; k0 += 32) {
            int kf = k0 + quad * 8;
            int am = wave * 16 + l15;
            bfrag ah = *(const bfrag*)&Ah[am * 72 + kf];
            bfrag al = *(const bfrag*)&Al[am * 72 + kf];
            #pragma unroll
            for (int j = 0; j < 4; ++j) {
                int bn = j * 16 + l15;
                bfrag bhf = *(const bfrag*)&Bh[bn * 72 + kf];
                bfrag blf = *(const bfrag*)&Bl[bn * 72 + kf];
                acc[j] = __builtin_amdgcn_mfma_f32_16x16x32_bf16(al, bhf, acc[j], 0, 0, 0);
                acc[j] = __builtin_amdgcn_mfma_f32_16x16x32_bf16(ah, blf, acc[j], 0, 0, 0);
                acc[j] = __builtin_amdgcn_mfma_f32_16x16x32_bf16(ah, bhf, acc[j], 0, 0, 0);
            }
        }
    }

    size_t cbase = (size_t)bh * 256 * N;
    if (Cf) {
        #pragma unroll
        for (int j = 0; j < 4; ++j) {
            #pragma unroll
            for (int r = 0; r < 4; ++r) {
                int row = m0 + wave * 16 + quad * 4 + r;
                Cf[cbase + (size_t)row * N + n0 + j * 16 + l15] = acc[j][r] * outscale;
            }
        }
    } else {
        #pragma unroll
        for (int j = 0; j < 4; ++j) {
            #pragma unroll
            for (int r = 0; r < 4; ++r) {
                int row = m0 + wave * 16 + quad * 4 + r;
                float val = acc[j][r] * outscale;
                unsigned short h, l;
                splitbf(val, h, l);
                size_t idx = cbase + (size_t)row * N + n0 + j * 16 + l15;
                Chp[idx] = h;
                Clp[idx] = l;
            }
        }
    }
}

// ---------------------------------------------------------------------------
// 4b) fused Moore-Penrose chain: 25 GEMM steps, one cooperative launch.
//     Grid = 256 blocks (bh = blk>>4, tile = blk&15 -> 64x64 output tile).
//     1 block/CU -> co-resident. grid.sync() + threadfence between steps.
// ---------------------------------------------------------------------------
__global__ __launch_bounds__(256) void k_pinv_chain(
    const unsigned short* xh, const unsigned short* xl,
    unsigned short* zh, unsigned short* zl,
    unsigned short* z2h, unsigned short* z2l,
    unsigned short* xzh, unsigned short* xzl,
    unsigned short* t2h, unsigned short* t2l,
    unsigned short* t3h, unsigned short* t3l,
    const unsigned short* kvh, const unsigned short* kvl,
    float* W)
{
    cg::grid_group grid = cg::this_grid();
    __shared__ __align__(16) unsigned short sm[4 * 64 * 72];

    int blk = blockIdx.x;
    int bh = blk >> 4;
    int tile = blk & 15;
    int m0 = (tile >> 2) * 64, n0 = (tile & 3) * 64;
    int t = threadIdx.x;

    unsigned short *zch = zh, *zcl = zl, *znh = z2h, *znl = z2l;

    for (int it = 0; it < 6; ++it) {
        // xz = x @ zc
        bmm_tile(sm, xh, xl, zch, zcl, xzh, xzl, nullptr, 256, 0.f, 0u, 1.f, bh, m0, n0, t);
        __threadfence(); grid.sync();
        // t2 = xz @ (7I - xz)
        bmm_tile(sm, xzh, xzl, xzh, xzl, t2h, t2l, nullptr, 256, 7.f, 0x8000u, 1.f, bh, m0, n0, t);
        __threadfence(); grid.sync();
        // t3 = xz @ (15I - t2)
        bmm_tile(sm, xzh, xzl, t2h, t2l, t3h, t3l, nullptr, 256, 15.f, 0x8000u, 1.f, bh, m0, n0, t);
        __threadfence(); grid.sync();
        // zn = 0.25 * zc @ (13I - t3)
        bmm_tile(sm, zch, zcl, t3h, t3l, znh, znl, nullptr, 256, 13.f, 0x8000u, 0.25f, bh, m0, n0, t);
        __threadfence(); grid.sync();
        unsigned short* th = zch; zch = znh; znh = th;
        unsigned short* tl = zcl; zcl = znl; znl = tl;
    }
    // W = zc @ kv   [256x256 @ 256x64] fp32 out; only n0==0 tiles participate
    if (n0 == 0)
        bmm_tile(sm, zch, zcl, kvh, kvl, nullptr, nullptr, W, 64, 0.f, 0u, 1.f, bh, m0, 0, t);
}

// ---------------------------------------------------------------------------
// 5a) attn3 flash partial, MFMA bf16 hi/lo split. (round 8, unchanged)
// ---------------------------------------------------------------------------
__global__ __launch_bounds__(256, 2) void k_attn3_partial(
    const float* __restrict__ ql, const float* __restrict__ k,
    const float* __restrict__ v, float* __restrict__ pO,
    float* __restrict__ pm, float* __restrict__ pl)
{
    __shared__ __align__(16) unsigned short sm3[36864];
    unsigned short* QH = sm3;
    unsigned short* QL = sm3 + 4608;
    unsigned short* KH = sm3 + 9216;
    unsigned short* KL = sm3 + 13824;
    unsigned short* VH = sm3 + 18432;
    unsigned short* VL = sm3 + 23040;
    unsigned short* PH = sm3 + 27648;
    unsigned short* PL = sm3 + 32256;

    int sp = blockIdx.x;              // 0..7, 1024 keys each
    int m0 = blockIdx.y * 64;         // landmark rows
    int bh = blockIdx.z;
    int t = threadIdx.x;
    int wave = t >> 6, lane = t & 63;
    int l15 = lane & 15, quad = lane >> 4;

    {   // stage Q once: 64 rows x 64 d, natural [m][d]
        int row = t & 63, ds = (t >> 6) * 16;
        const float* src = ql + ((size_t)bh * MLAND + m0 + row) * DHEAD + ds;
        stage16(src, &QH[row * 72 + ds], &QL[row * 72 + ds]);
    }
    __syncthreads();

    bfrag aqh[2], aql[2];
    #pragma unroll
    for (int ks = 0; ks < 2; ++ks) {
        aqh[ks] = *(const bfrag*)&QH[(wave * 16 + l15) * 72 + ks * 32 + quad * 8];
        aql[ks] = *(const bfrag*)&QL[(wave * 16 + l15) * 72 + ks * 32 + quad * 8];
    }

    f32x4 O[4] = {};                  // d-tile ni; lane holds rows quad*4+r
    float M[4], L[4];
    #pragma unroll
    for (int r = 0; r < 4; ++r) { M[r] = -1e30f; L[r] = 0.f; }

    const float* kb = k + (size_t)bh * N_SEQ * DHEAD;
    const float* vb = v + (size_t)bh * N_SEQ * DHEAD;

    for (int cc = 0; cc < 16; ++cc) {
        int c0 = sp * 1024 + cc * 64;
        __syncthreads();              // prev chunk's K/V reads done
        {   // K natural [key][d]
            int key = t & 63, ds = (t >> 6) * 16;
            stage16(kb + (size_t)(c0 + key) * DHEAD + ds,
                    &KH[key * 72 + ds], &KL[key * 72 + ds]);
        }
        {   // V transposed [d][key]
            int key = t & 63, dq = (t >> 6) * 16;
            const float* src = vb + (size_t)(c0 + key) * DHEAD + dq;
            #pragma unroll
            for (int o = 0; o < 16; o += 4) {
                float4 a = *(const float4*)(src + o);
                float vv[4] = {a.x, a.y, a.z, a.w};
                #pragma unroll
                for (int u = 0; u < 4; ++u) {
                    unsigned short h, l;
                    splitbf(vv[u], h, l);
                    VH[(dq + o + u) * 72 + key] = h;
                    VL[(dq + o + u) * 72 + key] = l;
                }
            }
        }
        __syncthreads();

        // --- QK^T ---
        f32x4 S4[4] = {};
        __builtin_amdgcn_s_setprio(1);
        #pragma unroll
        for (int ks = 0; ks < 2; ++ks) {
            #pragma unroll
            for (int ni = 0; ni < 4; ++ni) {
                bfrag bkh = *(const bfrag*)&KH[(ni * 16 + l15) * 72 + ks * 32 + quad * 8];
                bfrag bkl = *(const bfrag*)&KL[(ni * 16 + l15) * 72 + ks * 32 + quad * 8];
                S4[ni] = __builtin_amdgcn_mfma_f32_16x16x32_bf16(aql[ks], bkh, S4[ni], 0, 0, 0);
                S4[ni] = __builtin_amdgcn_mfma_f32_16x16x32_bf16(aqh[ks], bkl, S4[ni], 0, 0, 0);
                S4[ni] = __builtin_amdgcn_mfma_f32_16x16x32_bf16(aqh[ks], bkh, S4[ni], 0, 0, 0);
            }
        }
        __builtin_amdgcn_s_setprio(0);

        // --- online softmax ---
        #pragma unroll
        for (int r = 0; r < 4; ++r) {
            float mv = fmaxf(fmaxf(S4[0][r], S4[1][r]), fmaxf(S4[2][r], S4[3][r]));
            mv = fmaxf(mv, __shfl_xor(mv, 1, 16));
            mv = fmaxf(mv, __shfl_xor(mv, 2, 16));
            mv = fmaxf(mv, __shfl_xor(mv, 4, 16));
            mv = fmaxf(mv, __shfl_xor(mv, 8, 16));
            float nM = fmaxf(M[r], mv);
            float alpha = __expf(M[r] - nM);
            M[r] = nM;
            float rs = 0.f;
            #pragma unroll
            for (int ni = 0; ni < 4; ++ni) {
                float p = __expf(S4[ni][r] - nM);
                S4[ni][r] = p;
                rs += p;
            }
            rs += __shfl_xor(rs, 1, 16);
            rs += __shfl_xor(rs, 2, 16);
            rs += __shfl_xor(rs, 4, 16);
            rs += __shfl_xor(rs, 8, 16);
            L[r] = L[r] * alpha + rs;
            #pragma unroll
            for (int ni = 0; ni < 4; ++ni) O[ni][r] *= alpha;
        }

        // --- P -> LDS hi/lo (same-wave region) ---
        #pragma unroll
        for (int ni = 0; ni < 4; ++ni) {
            #pragma unroll
            for (int r = 0; r < 4; ++r) {
                int row = wave * 16 + quad * 4 + r;
                int col = ni * 16 + l15;
                unsigned short h, l;
                splitbf(S4[ni][r], h, l);
                PH[row * 72 + col] = h;
                PL[row * 72 + col] = l;
            }
        }

        // --- PV ---
        __builtin_amdgcn_s_setprio(1);
        #pragma unroll
        for (int ks = 0; ks < 2; ++ks) {
            bfrag aph = *(const bfrag*)&PH[(wave * 16 + l15) * 72 + ks * 32 + quad * 8];
            bfrag apl = *(const bfrag*)&PL[(wave * 16 + l15) * 72 + ks * 32 + quad * 8];
            #pragma unroll
            for (int ni = 0; ni < 4; ++ni) {
                bfrag bvh = *(const bfrag*)&VH[(ni * 16 + l15) * 72 + ks * 32 + quad * 8];
                bfrag bvl = *(const bfrag*)&VL[(ni * 16 + l15) * 72 + ks * 32 + quad * 8];
                O[ni] = __builtin_amdgcn_mfma_f32_16x16x32_bf16(apl, bvh, O[ni], 0, 0, 0);
                O[ni] = __builtin_amdgcn_mfma_f32_16x16x32_bf16(aph, bvl, O[ni], 0, 0, 0);
                O[ni] = __builtin_amdgcn_mfma_f32_16x16x32_bf16(aph, bvh, O[ni], 0, 0, 0);
            }
        }
        __builtin_amdgcn_s_setprio(0);
    }

    int base = (bh * NSPLIT3 + sp) * MLAND + m0;
    #pragma unroll
    for (int r = 0; r < 4; ++r) {
        int row = wave * 16 + quad * 4 + r;
        if (l15 == 0) { pm[base + row] = M[r]; pl[base + row] = L[r]; }
        #pragma unroll
        for (int ni = 0; ni < 4; ++ni)
            pO[(size_t)(base + row) * DHEAD + ni * 16 + l15] = O[ni][r];
    }
}

// ---------------------------------------------------------------------------
// 5b) combine 8 splits -> kv planes (split bf16)
// ---------------------------------------------------------------------------
__global__ __launch_bounds__(64) void k_attn3_combine(
    const float* __restrict__ pO, const float* __restrict__ pm,
    const float* __restrict__ pl, unsigned short* __restrict__ kvs)
{
    unsigned short* kvh = kvs;
    unsigned short* kvl = kvs + LM_E;
    int bh = blockIdx.x >> 8;
    int m  = blockIdx.x & 255;
    int d  = threadIdx.x;
    float M = -1e30f;
    #pragma unroll
    for (int s = 0; s < NSPLIT3; ++s) M = fmaxf(M, pm[(bh * NSPLIT3 + s) * MLAND + m]);
    float L = 0.f, O = 0.f;
    #pragma unroll
    for (int s = 0; s < NSPLIT3; ++s) {
        int base = (bh * NSPLIT3 + s) * MLAND + m;
        float w = __expf(pm[base] - M);
        L += pl[base] * w;
        O += w * pO[(size_t)base * DHEAD + d];
    }
    float val = O / L;
    unsigned short h, l;
    splitbf(val, h, l);
    size_t idx = ((size_t)bh * MLAND + m) * DHEAD + d;
    kvh[idx] = h;
    kvl[idx] = l;
}

// ---------------------------------------------------------------------------
// 6) out = softmax(q @ kl^T) @ W, MFMA fp16 hi/lo split. (round 11, unchanged)
// ---------------------------------------------------------------------------
__global__ __launch_bounds__(256, 2) void k_attn1_mfma(
    const float* __restrict__ q, const float* __restrict__ kl,
    const float* __restrict__ W, float* __restrict__ out)
{
    __shared__ __align__(16) unsigned short sm1[36864];
    unsigned short* QH = sm1;
    unsigned short* QL = sm1 + 4608;
    unsigned short* KH = sm1 + 9216;
    unsigned short* KL = sm1 + 13824;
    unsigned short* WH = sm1 + 18432;
    unsigned short* WL = sm1 + 23040;
    unsigned short* PH = sm1 + 27648;
    unsigned short* PL = sm1 + 32256;

    int bh = blockIdx.y;
    int r0 = blockIdx.x * 64;
    int t = threadIdx.x;
    int wave = t >> 6, lane = t & 63;
    int l15 = lane & 15, quad = lane >> 4;

    {   // stage Q once: 64 rows x 64 d, natural [m][d], fp16 hi/lo
        int row = t & 63, ds = (t >> 6) * 16;
        const float* src = q + ((size_t)bh * N_SEQ + r0 + row) * DHEAD + ds;
        stageh16(src, &QH[row * 72 + ds], &QL[row * 72 + ds]);
    }
    __syncthreads();

    hfrag aqh[2], aql[2];
    #pragma unroll
    for (int ks = 0; ks < 2; ++ks) {
        aqh[ks] = *(const hfrag*)&QH[(wave * 16 + l15) * 72 + ks * 32 + quad * 8];
        aql[ks] = *(const hfrag*)&QL[(wave * 16 + l15) * 72 + ks * 32 + quad * 8];
    }

    f32x4 O4[4] = {};                 // d-tile ni; lane holds rows quad*4+r
    float M[4], L[4];
    #pragma unroll
    for (int r = 0; r < 4; ++r) { M[r] = -1e30f; L[r] = 0.f; }

    for (int mc = 0; mc < 4; ++mc) {
        __syncthreads();              // prev chunk's KL/W reads done
        {   // kl chunk natural [land][d], fp16 hi/lo
            int key = t & 63, ds = (t >> 6) * 16;
            stageh16(kl + ((size_t)bh * MLAND + mc * 64 + key) * DHEAD + ds,
                     &KH[key * 72 + ds], &KL[key * 72 + ds]);
        }
        {   // W chunk transposed [d][land], scaled 1/64, fp16 hi/lo
            int key = t & 63, dq = (t >> 6) * 16;
            const float* src = W + ((size_t)bh * MLAND + mc * 64 + key) * DHEAD + dq;
            #pragma unroll
            for (int o = 0; o < 16; o += 4) {
                float4 a = *(const float4*)(src + o);
                float vv[4] = {a.x * 0.015625f, a.y * 0.015625f,
                               a.z * 0.015625f, a.w * 0.015625f};
                #pragma unroll
                for (int u = 0; u < 4; ++u) {
                    unsigned short h, l;
                    splith(vv[u], h, l);
                    WH[(dq + o + u) * 72 + key] = h;
                    WL[(dq + o + u) * 72 + key] = l;
                }
            }
        }
        __syncthreads();

        // --- q @ kl^T (fp16 hi/lo, 3 products) ---
        f32x4 S4[4] = {};
        __builtin_amdgcn_s_setprio(1);
        #pragma unroll
        for (int ks = 0; ks < 2; ++ks) {
            #pragma unroll
            for (int ni = 0; ni < 4; ++ni) {
                hfrag bkh = *(const hfrag*)&KH[(ni * 16 + l15) * 72 + ks * 32 + quad * 8];
                hfrag bkl = *(const hfrag*)&KL[(ni * 16 + l15) * 72 + ks * 32 + quad * 8];
                S4[ni] = __builtin_amdgcn_mfma_f32_16x16x32_f16(aql[ks], bkh, S4[ni], 0, 0, 0);
                S4[ni] = __builtin_amdgcn_mfma_f32_16x16x32_f16(aqh[ks], bkl, S4[ni], 0, 0, 0);
                S4[ni] = __builtin_amdgcn_mfma_f32_16x16x32_f16(aqh[ks], bkh, S4[ni], 0, 0, 0);
            }
        }
        __builtin_amdgcn_s_setprio(0);

        // --- online softmax (16-lane row groups) ---
        #pragma unroll
        for (int r = 0; r < 4; ++r) {
            float mv = fmaxf(fmaxf(S4[0][r], S4[1][r]), fmaxf(S4[2][r], S4[3][r]));
            mv = fmaxf(mv, __shfl_xor(mv, 1, 16));
            mv = fmaxf(mv, __shfl_xor(mv, 2, 16));
            mv = fmaxf(mv, __shfl_xor(mv, 4, 16));
            mv = fmaxf(mv, __shfl_xor(mv, 8, 16));
            float nM = fmaxf(M[r], mv);
            float alpha = __expf(M[r] - nM);
            M[r] = nM;
            float rs = 0.f;
            #pragma unroll
            for (int ni = 0; ni < 4; ++ni) {
                float p = __expf(S4[ni][r] - nM);
                S4[ni][r] = p;
                rs += p;
            }
            rs += __shfl_xor(rs, 1, 16);
            rs += __shfl_xor(rs, 2, 16);
            rs += __shfl_xor(rs, 4, 16);
            rs += __shfl_xor(rs, 8, 16);
            L[r] = L[r] * alpha + rs;
            #pragma unroll
            for (int ni = 0; ni < 4; ++ni) O4[ni][r] *= alpha;
        }

        // --- P -> LDS fp16 hi/lo (same-wave region) ---
        #pragma unroll
        for (int ni = 0; ni < 4; ++ni) {
            #pragma unroll
            for (int r = 0; r < 4; ++r) {
                int row = wave * 16 + quad * 4 + r;
                int col = ni * 16 + l15;
                unsigned short h, l;
                splith(S4[ni][r], h, l);
                PH[row * 72 + col] = h;
                PL[row * 72 + col] = l;
            }
        }

        // --- P @ W (fp16 hi/lo, 3 products) ---
        __builtin_amdgcn_s_setprio(1);
        #pragma unroll
        for (int ks = 0; ks < 2; ++ks) {
            hfrag aph = *(const hfrag*)&PH[(wave * 16 + l15) * 72 + ks * 32 + quad * 8];
            hfrag apl = *(const hfrag*)&PL[(wave * 16 + l15) * 72 + ks * 32 + quad * 8];
            #pragma unroll
            for (int ni = 0; ni < 4; ++ni) {
                hfrag bwh = *(const hfrag*)&WH[(ni * 16 + l15) * 72 + ks * 32 + quad * 8];
                hfrag bwl = *(const hfrag*)&WL[(ni * 16 + l15) * 72 + ks * 32 + quad * 8];
                O4[ni] = __builtin_amdgcn_mfma_f32_16x16x32_f16(apl, bwh, O4[ni], 0, 0, 0);
                O4[ni] = __builtin_amdgcn_mfma_f32_16x16x32_f16(aph, bwl, O4[ni], 0, 0, 0);
                O4[ni] = __builtin_amdgcn_mfma_f32_16x16x32_f16(aph, bwh, O4[ni], 0, 0, 0);
            }
        }
        __builtin_amdgcn_s_setprio(0);
    }

    // direct store: out[row][d] = O * (64/L)
    float inv[4];
    #pragma unroll
    for (int r = 0; r < 4; ++r) inv[r] = 64.0f / L[r];
    #pragma unroll
    for (int r = 0; r < 4; ++r) {
        int row = wave * 16 + quad * 4 + r;
        float* dst = out + ((size_t)bh * N_SEQ + r0 + row) * DHEAD;
        #pragma unroll
        for (int ni = 0; ni < 4; ++ni)
            dst[ni * 16 + l15] = O4[ni][r] * inv[r];
    }
}

// ---------------------------------------------------------------------------
// 7) out += conv33(v). (round 7-verified, unchanged)
// ---------------------------------------------------------------------------
__global__ __launch_bounds__(256) void k_conv_add(
    const float* __restrict__ v, const float* __restrict__ cw,
    float* __restrict__ out)
{
    __shared__ __align__(16) float smem[160 * 68];
    __shared__ float wgt[33];
    int bh = blockIdx.y;
    int r0 = blockIdx.x * 128;
    int t = threadIdx.x;
    int wave = t >> 6, lane = t & 63;
    int ly = lane >> 3, lx = lane & 7;
    int rb = wave * 32 + ly * 4;

    if (t < 33) wgt[t] = cw[(bh & 7) * 33 + t];

    for (int rr = t; rr < 160; rr += 256) {
        int gr = r0 - 16 + rr;
        bool ok = (gr >= 0) && (gr < N_SEQ);
        const float* src = v + ((size_t)bh * N_SEQ + gr) * DHEAD;
        #pragma unroll
        for (int c = 0; c < 64; c += 4) {
            float4 val = ok ? *(const float4*)(src + c) : make_float4(0.f, 0.f, 0.f, 0.f);
            *(float4*)&smem[rr * 68 + c] = val;
        }
    }
    __syncthreads();

    float res[4][8] = {};
    #pragma unroll
    for (int w = 0; w < 36; ++w) {
        float4 va  = *(const float4*)&smem[(rb + w) * 68 + lx * 8];
        float4 vb4 = *(const float4*)&smem[(rb + w) * 68 + lx * 8 + 4];
        #pragma unroll
        for (int i = 0; i < 4; ++i) {
            if (w - i >= 0 && w - i <= 32) {
                float wv = wgt[w - i];
                fma8(res[i], wv, va, vb4);
            }
        }
    }

    #pragma unroll
    for (int i = 0; i < 4; ++i) {
        float* dst = out + ((size_t)bh * N_SEQ + r0 + rb + i) * DHEAD + lx * 8;
        float4 o0 = *(const float4*)dst;
        float4 o1 = *(const float4*)(dst + 4);
        *(float4*)dst = make_float4(o0.x + res[i][0], o0.y + res[i][1],
                                    o0.z + res[i][2], o0.w + res[i][3]);
        *(float4*)(dst + 4) = make_float4(o1.x + res[i][4], o1.y + res[i][5],
                                          o1.z + res[i][6], o1.w + res[i][7]);
    }
}

// ---------------------------------------------------------------------------
// launch
// ---------------------------------------------------------------------------
extern "C" void kernel_launch(void* const* d_in, const int* in_sizes, int n_in,
                              void* d_out, int out_size, void* d_ws, size_t ws_size,
                              hipStream_t stream)
{
    (void)in_sizes; (void)n_in; (void)out_size; (void)ws_size;
    const float* q  = (const float*)d_in[0];
    const float* k  = (const float*)d_in[1];
    const float* v  = (const float*)d_in[2];
    const float* cw = (const float*)d_in[3];
    float* out = (float*)d_out;
    float* ws  = (float*)d_ws;

    const size_t LM = (size_t)LM_E;   // 262144 floats
    const size_t MM = (size_t)MM_E;   // 1048576 floats

    // float-unit layout (total ~29.6 MB, <= proven 29.9 MB):
    float* ql  = ws;                  // LM
    float* kl  = ql  + LM;            // LM
    float* xsf = kl  + LM;            // MM floats  = xh|xl planes (2*MM ushorts)
    float* zsf = xsf + MM;            // MM floats  = zh|zl planes
    float* big = zsf + MM;            // 4*MM floats: pO (2*MM fl) then 8 planes
    float* kvf = big + 4 * MM;        // LM floats  = kvh|kvl planes
    float* W   = kvf + LM;            // LM floats
    float* scl = W   + LM;            // 16
    float* pm  = scl + 16;            // NBH*NSPLIT3*MLAND
    float* pl  = pm + (size_t)NBH * NSPLIT3 * MLAND;

    float* pO = big;                  // 2*MM floats, dead before pinv chain

    unsigned short* xs  = (unsigned short*)xsf;
    unsigned short* zs  = (unsigned short*)zsf;
    unsigned short* bgu = (unsigned short*)big;   // 8*MM ushorts
    unsigned short* kvs = (unsigned short*)kvf;

    unsigned short* xh  = xs;
    unsigned short* xl  = xs + MM;
    unsigned short* zh  = zs;
    unsigned short* zl  = zs + MM;
    unsigned short* z2h = bgu;
    unsigned short* z2l = bgu + MM;
    unsigned short* xzh = bgu + 2 * MM;
    unsigned short* xzl = bgu + 3 * MM;
    unsigned short* t2h = bgu + 4 * MM;
    unsigned short* t2l = bgu + 5 * MM;
    unsigned short* t3h = bgu + 6 * MM;
    unsigned short* t3l = bgu + 7 * MM;
    unsigned short* kvh = kvs;
    unsigned short* kvl = kvs + LM;

    hipMemsetAsync(scl, 0, 32, stream);

    k_landmarks<<<dim3(NBH * MLAND, 2), 64, 0, stream>>>(q, k, ql, kl);
    k_sim2_softmax<<<NBH * MLAND, 256, 0, stream>>>(ql, kl, xs);
    k_scale_reduce<<<NBH, 256, 0, stream>>>(xs, scl);
    k_zinit<<<dim3(8, 8, NBH), 256, 0, stream>>>(xs, zs, scl);

    k_attn3_partial<<<dim3(NSPLIT3, 4, NBH), 256, 0, stream>>>(ql, k, v, pO, pm, pl);
    k_attn3_combine<<<NBH * MLAND, 64, 0, stream>>>(pO, pm, pl, kvs);

    // Moore-Penrose chain: one cooperative launch, 25 GEMM steps inside.
    {
        void* args[] = {
            (void*)&xh, (void*)&xl,
            (void*)&zh, (void*)&zl,
            (void*)&z2h, (void*)&z2l,
            (void*)&xzh, (void*)&xzl,
            (void*)&t2h, (void*)&t2l,
            (void*)&t3h, (void*)&t3l,
            (void*)&kvh, (void*)&kvl,
            (void*)&W
        };
        hipLaunchCooperativeKernel((const void*)k_pinv_chain,
                                   dim3(256), dim3(256), args, 0, stream);
    }

    k_attn1_mfma<<<dim3(128, NBH), 256, 0, stream>>>(q, kl, W, out);
    k_conv_add<<<dim3(64, NBH), 256, 0, stream>>>(v, cw, out);
}

// Round 7
// 600.562 us; speedup vs baseline: 3.4244x; 3.4244x over previous
//
#include <hip/hip_runtime.h>

// ---------------------------------------------------------------------------
// Nystrom attention, fp32. b=2,h=8,n=8192,d=64, m=256 landmarks, conv33.
// Round 14: revert coop chain (grid.sync = 70us + L2 flush on MI355X).
// Back to round-12 stream-ordered chain, but bmm retiled 64x64 -> 32x64:
// 512 blocks = 2 blocks/CU = 2 waves/SIMD (was 1) to hide memory latency.
// ---------------------------------------------------------------------------

#define N_SEQ 8192
#define NBH   16
#define MLAND 256
#define DHEAD 64
#define NSPLIT3 8
#define MM_E  (NBH * MLAND * MLAND)   // 1048576 elements per plane
#define LM_E  (NBH * MLAND * DHEAD)   // 262144

typedef __attribute__((ext_vector_type(8))) short bfrag;
typedef __attribute__((ext_vector_type(8))) _Float16 hfrag;
typedef __attribute__((ext_vector_type(4))) float f32x4;

__device__ __forceinline__ void fma8(float (&o)[8], float p, const float4& a, const float4& b) {
    o[0] += p * a.x; o[1] += p * a.y; o[2] += p * a.z; o[3] += p * a.w;
    o[4] += p * b.x; o[5] += p * b.y; o[6] += p * b.z; o[7] += p * b.w;
}

__device__ __forceinline__ float bf2f(unsigned short h) {
    return __uint_as_float(((unsigned)h) << 16);
}

// truncation hi/lo split (bf16): hi = top 16 bits, lo = bf16(v - hi).
__device__ __forceinline__ void splitbf(float v, unsigned short& h, unsigned short& l) {
    unsigned bits = __float_as_uint(v);
    h = (unsigned short)(bits >> 16);
    float r = v - __uint_as_float(bits & 0xffff0000u);
    l = (unsigned short)(__float_as_uint(r) >> 16);
}

// fp16 hi/lo split: ~22 mantissa bits total. h = rn(v), l = rn(v - h).
__device__ __forceinline__ void splith(float v, unsigned short& h, unsigned short& l) {
    _Float16 hf = (_Float16)v;
    _Float16 lf = (_Float16)(v - (float)hf);
    h = __builtin_bit_cast(unsigned short, hf);
    l = __builtin_bit_cast(unsigned short, lf);
}

// read 16 consecutive floats, write hi/lo ushorts u32-packed (bf16 version)
__device__ __forceinline__ void stage16(const float* __restrict__ src,
                                        unsigned short* dh, unsigned short* dl) {
    unsigned* ph = (unsigned*)dh;
    unsigned* pl = (unsigned*)dl;
    #pragma unroll
    for (int o = 0; o < 16; o += 4) {
        float4 a = *(const float4*)(src + o);
        float vv[4] = {a.x, a.y, a.z, a.w};
        unsigned short h[4], l[4];
        #pragma unroll
        for (int u = 0; u < 4; ++u) splitbf(vv[u], h[u], l[u]);
        ph[o / 2]     = (unsigned)h[0] | ((unsigned)h[1] << 16);
        ph[o / 2 + 1] = (unsigned)h[2] | ((unsigned)h[3] << 16);
        pl[o / 2]     = (unsigned)l[0] | ((unsigned)l[1] << 16);
        pl[o / 2 + 1] = (unsigned)l[2] | ((unsigned)l[3] << 16);
    }
}

// fp16 version of stage16
__device__ __forceinline__ void stageh16(const float* __restrict__ src,
                                         unsigned short* dh, unsigned short* dl) {
    unsigned* ph = (unsigned*)dh;
    unsigned* pl = (unsigned*)dl;
    #pragma unroll
    for (int o = 0; o < 16; o += 4) {
        float4 a = *(const float4*)(src + o);
        float vv[4] = {a.x, a.y, a.z, a.w};
        unsigned short h[4], l[4];
        #pragma unroll
        for (int u = 0; u < 4; ++u) splith(vv[u], h[u], l[u]);
        ph[o / 2]     = (unsigned)h[0] | ((unsigned)h[1] << 16);
        ph[o / 2 + 1] = (unsigned)h[2] | ((unsigned)h[3] << 16);
        pl[o / 2]     = (unsigned)l[0] | ((unsigned)l[1] << 16);
        pl[o / 2 + 1] = (unsigned)l[2] | ((unsigned)l[3] << 16);
    }
}

// ---------------------------------------------------------------------------
// 1) landmark means
// ---------------------------------------------------------------------------
__global__ __launch_bounds__(64) void k_landmarks(
    const float* __restrict__ q, const float* __restrict__ k,
    float* __restrict__ ql, float* __restrict__ kl)
{
    int mi = blockIdx.x & 255;
    int bh = blockIdx.x >> 8;
    const float* src = blockIdx.y ? k : q;
    float*       dst = blockIdx.y ? kl : ql;
    int t = threadIdx.x;
    const float* s = src + ((size_t)bh * N_SEQ + (size_t)mi * 32) * DHEAD;
    float acc = 0.f;
    #pragma unroll
    for (int j = 0; j < 32; ++j) acc += s[j * DHEAD + t];
    dst[((size_t)bh * MLAND + mi) * DHEAD + t] = acc * (1.f / 32.f);
}

// ---------------------------------------------------------------------------
// 2) attn2 = softmax(ql @ kl^T) rowwise -> split bf16 planes (xh|xl)
// ---------------------------------------------------------------------------
__global__ __launch_bounds__(256) void k_sim2_softmax(
    const float* __restrict__ ql, const float* __restrict__ kl,
    unsigned short* __restrict__ xs)
{
    unsigned short* xh = xs;
    unsigned short* xl = xs + MM_E;
    int bh = blockIdx.x >> 8;
    int i  = blockIdx.x & 255;
    int t  = threadIdx.x;
    __shared__ float qrow[DHEAD];
    __shared__ float wred[8];
    if (t < DHEAD) qrow[t] = ql[((size_t)bh * MLAND + i) * DHEAD + t];
    __syncthreads();
    const float* krow = kl + ((size_t)bh * MLAND + t) * DHEAD;
    float s = 0.f;
    #pragma unroll
    for (int kk = 0; kk < DHEAD; kk += 4) {
        float4 k4 = *(const float4*)(krow + kk);
        s += qrow[kk] * k4.x + qrow[kk + 1] * k4.y + qrow[kk + 2] * k4.z + qrow[kk + 3] * k4.w;
    }
    float m = s;
    #pragma unroll
    for (int o = 32; o > 0; o >>= 1) m = fmaxf(m, __shfl_xor(m, o, 64));
    int wave = t >> 6, lane = t & 63;
    if (lane == 0) wred[wave] = m;
    __syncthreads();
    float bm = fmaxf(fmaxf(wred[0], wred[1]), fmaxf(wred[2], wred[3]));
    float e = __expf(s - bm);
    float sum = e;
    #pragma unroll
    for (int o = 32; o > 0; o >>= 1) sum += __shfl_xor(sum, o, 64);
    if (lane == 0) wred[4 + wave] = sum;
    __syncthreads();
    float bs = wred[4] + wred[5] + wred[6] + wred[7];
    float val = e / bs;
    unsigned short h, l;
    splitbf(val, h, l);
    size_t idx = ((size_t)bh * MLAND + i) * MLAND + t;
    xh[idx] = h;
    xl[idx] = l;
}

// ---------------------------------------------------------------------------
// 3a) global max of row-sums and col-sums of attn2 (from planes)
// ---------------------------------------------------------------------------
__global__ __launch_bounds__(256) void k_scale_reduce(
    const unsigned short* __restrict__ xs, float* __restrict__ scl)
{
    const unsigned short* xh = xs;
    const unsigned short* xl = xs + MM_E;
    int bh = blockIdx.x, t = threadIdx.x;
    size_t b = (size_t)bh * MLAND * MLAND;
    float colsum = 0.f, rowsum = 0.f;
    for (int i = 0; i < MLAND; ++i) {
        size_t idx = b + (size_t)i * MLAND + t;
        colsum += bf2f(xh[idx]) + bf2f(xl[idx]);
    }
    for (int j = 0; j < MLAND; ++j) {
        size_t idx = b + (size_t)t * MLAND + j;
        rowsum += bf2f(xh[idx]) + bf2f(xl[idx]);
    }
    __shared__ float red[256];
    red[t] = rowsum;
    __syncthreads();
    for (int o = 128; o > 0; o >>= 1) {
        if (t < o) red[t] = fmaxf(red[t], red[t + o]);
        __syncthreads();
    }
    if (t == 0) atomicMax((unsigned int*)&scl[0], __float_as_uint(red[0]));
    __syncthreads();
    red[t] = colsum;
    __syncthreads();
    for (int o = 128; o > 0; o >>= 1) {
        if (t < o) red[t] = fmaxf(red[t], red[t + o]);
        __syncthreads();
    }
    if (t == 0) atomicMax((unsigned int*)&scl[1], __float_as_uint(red[0]));
}

// ---------------------------------------------------------------------------
// 3b) z0 = attn2^T / (scl[0]*scl[1])  (planes -> planes)
// ---------------------------------------------------------------------------
__global__ __launch_bounds__(256) void k_zinit(
    const unsigned short* __restrict__ xs, unsigned short* __restrict__ zs,
    const float* __restrict__ scl)
{
    const unsigned short* xh = xs;
    const unsigned short* xl = xs + MM_E;
    unsigned short* zh = zs;
    unsigned short* zl = zs + MM_E;
    __shared__ float tile[32][33];
    int bh = blockIdx.z;
    int i0 = blockIdx.y * 32, j0 = blockIdx.x * 32;
    int t = threadIdx.x;
    int lx = t & 31, ly = t >> 5;
    size_t b = (size_t)bh * MLAND * MLAND;
    #pragma unroll
    for (int p = 0; p < 4; ++p) {
        size_t idx = b + (size_t)(i0 + ly + 8 * p) * MLAND + j0 + lx;
        tile[ly + 8 * p][lx] = bf2f(xh[idx]) + bf2f(xl[idx]);
    }
    __syncthreads();
    float inv = 1.0f / (scl[0] * scl[1]);
    #pragma unroll
    for (int p = 0; p < 4; ++p) {
        float val = tile[lx][ly + 8 * p] * inv;
        unsigned short h, l;
        splitbf(val, h, l);
        size_t idx = b + (size_t)(j0 + ly + 8 * p) * MLAND + i0 + lx;
        zh[idx] = h;
        zl[idx] = l;
    }
}

// ---------------------------------------------------------------------------
// 4) plane bmm: C = outscale * (A @ (diag*I + bscale*B)); M=K=256, N param.
//    Round 14: 32x64 tiles, grid (N/64, 8, NBH) = 512 blocks -> 2 blocks/CU
//    -> 2 waves/SIMD latency hiding. Wave = 16x32 strip (acc[2]).
//    Staging/MFMA/diag logic byte-equivalent to verified round-12 kernel.
// ---------------------------------------------------------------------------
__global__ __launch_bounds__(256) void k_bmm_planes(
    const unsigned short* __restrict__ Ahp, const unsigned short* __restrict__ Alp,
    const unsigned short* __restrict__ Bhp, const unsigned short* __restrict__ Blp,
    unsigned short* __restrict__ Chp, unsigned short* __restrict__ Clp,
    float* __restrict__ Cf,
    int N, float diag, float bscale, float outscale)
{
    __shared__ unsigned short sm[2 * 32 * 72 + 2 * 64 * 72];   // Ah|Al|Bh|Bl 27.6KB
    unsigned short* Ah = sm;
    unsigned short* Al = sm + 32 * 72;
    unsigned short* Bh = sm + 2 * 32 * 72;
    unsigned short* Bl = sm + 2 * 32 * 72 + 64 * 72;

    int bh = blockIdx.z;
    const size_t abase = (size_t)bh * 65536;
    const size_t bbase = (size_t)bh * 256 * N;
    int m0 = blockIdx.y * 32, n0 = blockIdx.x * 64;
    int t = threadIdx.x;
    int wave = t >> 6, lane = t & 63;
    int l15 = lane & 15, quad = lane >> 4;
    int wr = wave >> 1, wc = wave & 1;          // wave strip: rows wr*16, cols wc*32
    unsigned sflip = (bscale < 0.f) ? 0x8000u : 0u;

    f32x4 acc[2] = {};

    for (int kc = 0; kc < 256; kc += 64) {
        __syncthreads();
        {   // stage A rows natural [m][k], 32 rows: thread row m=t&31, 8 k's
            int m = t & 31, ks = (t >> 5) * 8;
            size_t off = abase + (size_t)(m0 + m) * 256 + kc + ks;
            *(uint4*)&Ah[m * 72 + ks] = *(const uint4*)&Ahp[off];
            *(uint4*)&Al[m * 72 + ks] = *(const uint4*)&Alp[off];
        }
        {   // stage B transposed [n][k]: vector load, sign-flip, scatter
            int kk = t & 63, ns = (t >> 6) * 16;
            int gk = kc + kk;
            size_t off = bbase + (size_t)gk * N + n0 + ns;
            unsigned short hb[16], lb[16];
            *(uint4*)&hb[0] = *(const uint4*)&Bhp[off];
            *(uint4*)&hb[8] = *(const uint4*)&Bhp[off + 8];
            *(uint4*)&lb[0] = *(const uint4*)&Blp[off];
            *(uint4*)&lb[8] = *(const uint4*)&Blp[off + 8];
            #pragma unroll
            for (int u = 0; u < 16; ++u) {
                unsigned short h = hb[u] ^ sflip;
                unsigned short l = lb[u] ^ sflip;
                if (diag != 0.f && gk == n0 + ns + u) {
                    float val = diag + bf2f(h) + bf2f(l);
                    splitbf(val, h, l);
                }
                Bh[(ns + u) * 72 + kk] = h;
                Bl[(ns + u) * 72 + kk] = l;
            }
        }
        __syncthreads();

        #pragma unroll
        for (int k0 = 0; k0 < 64; k0 += 32) {
            int kf = k0 + quad * 8;
            int am = wr * 16 + l15;
            bfrag ah = *(const bfrag*)&Ah[am * 72 + kf];
            bfrag al = *(const bfrag*)&Al[am * 72 + kf];
            #pragma unroll
            for (int j = 0; j < 2; ++j) {
                int bn = wc * 32 + j * 16 + l15;
                bfrag bhf = *(const bfrag*)&Bh[bn * 72 + kf];
                bfrag blf = *(const bfrag*)&Bl[bn * 72 + kf];
                acc[j] = __builtin_amdgcn_mfma_f32_16x16x32_bf16(al, bhf, acc[j], 0, 0, 0);
                acc[j] = __builtin_amdgcn_mfma_f32_16x16x32_bf16(ah, blf, acc[j], 0, 0, 0);
                acc[j] = __builtin_amdgcn_mfma_f32_16x16x32_bf16(ah, bhf, acc[j], 0, 0, 0);
            }
        }
    }

    size_t cbase = (size_t)bh * 256 * N;
    if (Cf) {
        #pragma unroll
        for (int j = 0; j < 2; ++j) {
            #pragma unroll
            for (int r = 0; r < 4; ++r) {
                int row = m0 + wr * 16 + quad * 4 + r;
                int col = n0 + wc * 32 + j * 16 + l15;
                Cf[cbase + (size_t)row * N + col] = acc[j][r] * outscale;
            }
        }
    } else {
        #pragma unroll
        for (int j = 0; j < 2; ++j) {
            #pragma unroll
            for (int r = 0; r < 4; ++r) {
                int row = m0 + wr * 16 + quad * 4 + r;
                int col = n0 + wc * 32 + j * 16 + l15;
                float val = acc[j][r] * outscale;
                unsigned short h, l;
                splitbf(val, h, l);
                size_t idx = cbase + (size_t)row * N + col;
                Chp[idx] = h;
                Clp[idx] = l;
            }
        }
    }
}

// ---------------------------------------------------------------------------
// 5a) attn3 flash partial, MFMA bf16 hi/lo split. (round 8, unchanged)
// ---------------------------------------------------------------------------
__global__ __launch_bounds__(256, 2) void k_attn3_partial(
    const float* __restrict__ ql, const float* __restrict__ k,
    const float* __restrict__ v, float* __restrict__ pO,
    float* __restrict__ pm, float* __restrict__ pl)
{
    __shared__ __align__(16) unsigned short sm3[36864];
    unsigned short* QH = sm3;
    unsigned short* QL = sm3 + 4608;
    unsigned short* KH = sm3 + 9216;
    unsigned short* KL = sm3 + 13824;
    unsigned short* VH = sm3 + 18432;
    unsigned short* VL = sm3 + 23040;
    unsigned short* PH = sm3 + 27648;
    unsigned short* PL = sm3 + 32256;

    int sp = blockIdx.x;              // 0..7, 1024 keys each
    int m0 = blockIdx.y * 64;         // landmark rows
    int bh = blockIdx.z;
    int t = threadIdx.x;
    int wave = t >> 6, lane = t & 63;
    int l15 = lane & 15, quad = lane >> 4;

    {   // stage Q once: 64 rows x 64 d, natural [m][d]
        int row = t & 63, ds = (t >> 6) * 16;
        const float* src = ql + ((size_t)bh * MLAND + m0 + row) * DHEAD + ds;
        stage16(src, &QH[row * 72 + ds], &QL[row * 72 + ds]);
    }
    __syncthreads();

    bfrag aqh[2], aql[2];
    #pragma unroll
    for (int ks = 0; ks < 2; ++ks) {
        aqh[ks] = *(const bfrag*)&QH[(wave * 16 + l15) * 72 + ks * 32 + quad * 8];
        aql[ks] = *(const bfrag*)&QL[(wave * 16 + l15) * 72 + ks * 32 + quad * 8];
    }

    f32x4 O[4] = {};                  // d-tile ni; lane holds rows quad*4+r
    float M[4], L[4];
    #pragma unroll
    for (int r = 0; r < 4; ++r) { M[r] = -1e30f; L[r] = 0.f; }

    const float* kb = k + (size_t)bh * N_SEQ * DHEAD;
    const float* vb = v + (size_t)bh * N_SEQ * DHEAD;

    for (int cc = 0; cc < 16; ++cc) {
        int c0 = sp * 1024 + cc * 64;
        __syncthreads();              // prev chunk's K/V reads done
        {   // K natural [key][d]
            int key = t & 63, ds = (t >> 6) * 16;
            stage16(kb + (size_t)(c0 + key) * DHEAD + ds,
                    &KH[key * 72 + ds], &KL[key * 72 + ds]);
        }
        {   // V transposed [d][key]
            int key = t & 63, dq = (t >> 6) * 16;
            const float* src = vb + (size_t)(c0 + key) * DHEAD + dq;
            #pragma unroll
            for (int o = 0; o < 16; o += 4) {
                float4 a = *(const float4*)(src + o);
                float vv[4] = {a.x, a.y, a.z, a.w};
                #pragma unroll
                for (int u = 0; u < 4; ++u) {
                    unsigned short h, l;
                    splitbf(vv[u], h, l);
                    VH[(dq + o + u) * 72 + key] = h;
                    VL[(dq + o + u) * 72 + key] = l;
                }
            }
        }
        __syncthreads();

        // --- QK^T ---
        f32x4 S4[4] = {};
        __builtin_amdgcn_s_setprio(1);
        #pragma unroll
        for (int ks = 0; ks < 2; ++ks) {
            #pragma unroll
            for (int ni = 0; ni < 4; ++ni) {
                bfrag bkh = *(const bfrag*)&KH[(ni * 16 + l15) * 72 + ks * 32 + quad * 8];
                bfrag bkl = *(const bfrag*)&KL[(ni * 16 + l15) * 72 + ks * 32 + quad * 8];
                S4[ni] = __builtin_amdgcn_mfma_f32_16x16x32_bf16(aql[ks], bkh, S4[ni], 0, 0, 0);
                S4[ni] = __builtin_amdgcn_mfma_f32_16x16x32_bf16(aqh[ks], bkl, S4[ni], 0, 0, 0);
                S4[ni] = __builtin_amdgcn_mfma_f32_16x16x32_bf16(aqh[ks], bkh, S4[ni], 0, 0, 0);
            }
        }
        __builtin_amdgcn_s_setprio(0);

        // --- online softmax ---
        #pragma unroll
        for (int r = 0; r < 4; ++r) {
            float mv = fmaxf(fmaxf(S4[0][r], S4[1][r]), fmaxf(S4[2][r], S4[3][r]));
            mv = fmaxf(mv, __shfl_xor(mv, 1, 16));
            mv = fmaxf(mv, __shfl_xor(mv, 2, 16));
            mv = fmaxf(mv, __shfl_xor(mv, 4, 16));
            mv = fmaxf(mv, __shfl_xor(mv, 8, 16));
            float nM = fmaxf(M[r], mv);
            float alpha = __expf(M[r] - nM);
            M[r] = nM;
            float rs = 0.f;
            #pragma unroll
            for (int ni = 0; ni < 4; ++ni) {
                float p = __expf(S4[ni][r] - nM);
                S4[ni][r] = p;
                rs += p;
            }
            rs += __shfl_xor(rs, 1, 16);
            rs += __shfl_xor(rs, 2, 16);
            rs += __shfl_xor(rs, 4, 16);
            rs += __shfl_xor(rs, 8, 16);
            L[r] = L[r] * alpha + rs;
            #pragma unroll
            for (int ni = 0; ni < 4; ++ni) O[ni][r] *= alpha;
        }

        // --- P -> LDS hi/lo (same-wave region) ---
        #pragma unroll
        for (int ni = 0; ni < 4; ++ni) {
            #pragma unroll
            for (int r = 0; r < 4; ++r) {
                int row = wave * 16 + quad * 4 + r;
                int col = ni * 16 + l15;
                unsigned short h, l;
                splitbf(S4[ni][r], h, l);
                PH[row * 72 + col] = h;
                PL[row * 72 + col] = l;
            }
        }

        // --- PV ---
        __builtin_amdgcn_s_setprio(1);
        #pragma unroll
        for (int ks = 0; ks < 2; ++ks) {
            bfrag aph = *(const bfrag*)&PH[(wave * 16 + l15) * 72 + ks * 32 + quad * 8];
            bfrag apl = *(const bfrag*)&PL[(wave * 16 + l15) * 72 + ks * 32 + quad * 8];
            #pragma unroll
            for (int ni = 0; ni < 4; ++ni) {
                bfrag bvh = *(const bfrag*)&VH[(ni * 16 + l15) * 72 + ks * 32 + quad * 8];
                bfrag bvl = *(const bfrag*)&VL[(ni * 16 + l15) * 72 + ks * 32 + quad * 8];
                O[ni] = __builtin_amdgcn_mfma_f32_16x16x32_bf16(apl, bvh, O[ni], 0, 0, 0);
                O[ni] = __builtin_amdgcn_mfma_f32_16x16x32_bf16(aph, bvl, O[ni], 0, 0, 0);
                O[ni] = __builtin_amdgcn_mfma_f32_16x16x32_bf16(aph, bvh, O[ni], 0, 0, 0);
            }
        }
        __builtin_amdgcn_s_setprio(0);
    }

    int base = (bh * NSPLIT3 + sp) * MLAND + m0;
    #pragma unroll
    for (int r = 0; r < 4; ++r) {
        int row = wave * 16 + quad * 4 + r;
        if (l15 == 0) { pm[base + row] = M[r]; pl[base + row] = L[r]; }
        #pragma unroll
        for (int ni = 0; ni < 4; ++ni)
            pO[(size_t)(base + row) * DHEAD + ni * 16 + l15] = O[ni][r];
    }
}

// ---------------------------------------------------------------------------
// 5b) combine 8 splits -> kv planes (split bf16)
// ---------------------------------------------------------------------------
__global__ __launch_bounds__(64) void k_attn3_combine(
    const float* __restrict__ pO, const float* __restrict__ pm,
    const float* __restrict__ pl, unsigned short* __restrict__ kvs)
{
    unsigned short* kvh = kvs;
    unsigned short* kvl = kvs + LM_E;
    int bh = blockIdx.x >> 8;
    int m  = blockIdx.x & 255;
    int d  = threadIdx.x;
    float M = -1e30f;
    #pragma unroll
    for (int s = 0; s < NSPLIT3; ++s) M = fmaxf(M, pm[(bh * NSPLIT3 + s) * MLAND + m]);
    float L = 0.f, O = 0.f;
    #pragma unroll
    for (int s = 0; s < NSPLIT3; ++s) {
        int base = (bh * NSPLIT3 + s) * MLAND + m;
        float w = __expf(pm[base] - M);
        L += pl[base] * w;
        O += w * pO[(size_t)base * DHEAD + d];
    }
    float val = O / L;
    unsigned short h, l;
    splitbf(val, h, l);
    size_t idx = ((size_t)bh * MLAND + m) * DHEAD + d;
    kvh[idx] = h;
    kvl[idx] = l;
}

// ---------------------------------------------------------------------------
// 6) out = softmax(q @ kl^T) @ W, MFMA fp16 hi/lo split. (round 11, unchanged)
// ---------------------------------------------------------------------------
__global__ __launch_bounds__(256, 2) void k_attn1_mfma(
    const float* __restrict__ q, const float* __restrict__ kl,
    const float* __restrict__ W, float* __restrict__ out)
{
    __shared__ __align__(16) unsigned short sm1[36864];
    unsigned short* QH = sm1;
    unsigned short* QL = sm1 + 4608;
    unsigned short* KH = sm1 + 9216;
    unsigned short* KL = sm1 + 13824;
    unsigned short* WH = sm1 + 18432;
    unsigned short* WL = sm1 + 23040;
    unsigned short* PH = sm1 + 27648;
    unsigned short* PL = sm1 + 32256;

    int bh = blockIdx.y;
    int r0 = blockIdx.x * 64;
    int t = threadIdx.x;
    int wave = t >> 6, lane = t & 63;
    int l15 = lane & 15, quad = lane >> 4;

    {   // stage Q once: 64 rows x 64 d, natural [m][d], fp16 hi/lo
        int row = t & 63, ds = (t >> 6) * 16;
        const float* src = q + ((size_t)bh * N_SEQ + r0 + row) * DHEAD + ds;
        stageh16(src, &QH[row * 72 + ds], &QL[row * 72 + ds]);
    }
    __syncthreads();

    hfrag aqh[2], aql[2];
    #pragma unroll
    for (int ks = 0; ks < 2; ++ks) {
        aqh[ks] = *(const hfrag*)&QH[(wave * 16 + l15) * 72 + ks * 32 + quad * 8];
        aql[ks] = *(const hfrag*)&QL[(wave * 16 + l15) * 72 + ks * 32 + quad * 8];
    }

    f32x4 O4[4] = {};                 // d-tile ni; lane holds rows quad*4+r
    float M[4], L[4];
    #pragma unroll
    for (int r = 0; r < 4; ++r) { M[r] = -1e30f; L[r] = 0.f; }

    for (int mc = 0; mc < 4; ++mc) {
        __syncthreads();              // prev chunk's KL/W reads done
        {   // kl chunk natural [land][d], fp16 hi/lo
            int key = t & 63, ds = (t >> 6) * 16;
            stageh16(kl + ((size_t)bh * MLAND + mc * 64 + key) * DHEAD + ds,
                     &KH[key * 72 + ds], &KL[key * 72 + ds]);
        }
        {   // W chunk transposed [d][land], scaled 1/64, fp16 hi/lo
            int key = t & 63, dq = (t >> 6) * 16;
            const float* src = W + ((size_t)bh * MLAND + mc * 64 + key) * DHEAD + dq;
            #pragma unroll
            for (int o = 0; o < 16; o += 4) {
                float4 a = *(const float4*)(src + o);
                float vv[4] = {a.x * 0.015625f, a.y * 0.015625f,
                               a.z * 0.015625f, a.w * 0.015625f};
                #pragma unroll
                for (int u = 0; u < 4; ++u) {
                    unsigned short h, l;
                    splith(vv[u], h, l);
                    WH[(dq + o + u) * 72 + key] = h;
                    WL[(dq + o + u) * 72 + key] = l;
                }
            }
        }
        __syncthreads();

        // --- q @ kl^T (fp16 hi/lo, 3 products) ---
        f32x4 S4[4] = {};
        __builtin_amdgcn_s_setprio(1);
        #pragma unroll
        for (int ks = 0; ks < 2; ++ks) {
            #pragma unroll
            for (int ni = 0; ni < 4; ++ni) {
                hfrag bkh = *(const hfrag*)&KH[(ni * 16 + l15) * 72 + ks * 32 + quad * 8];
                hfrag bkl = *(const hfrag*)&KL[(ni * 16 + l15) * 72 + ks * 32 + quad * 8];
                S4[ni] = __builtin_amdgcn_mfma_f32_16x16x32_f16(aql[ks], bkh, S4[ni], 0, 0, 0);
                S4[ni] = __builtin_amdgcn_mfma_f32_16x16x32_f16(aqh[ks], bkl, S4[ni], 0, 0, 0);
                S4[ni] = __builtin_amdgcn_mfma_f32_16x16x32_f16(aqh[ks], bkh, S4[ni], 0, 0, 0);
            }
        }
        __builtin_amdgcn_s_setprio(0);

        // --- online softmax (16-lane row groups) ---
        #pragma unroll
        for (int r = 0; r < 4; ++r) {
            float mv = fmaxf(fmaxf(S4[0][r], S4[1][r]), fmaxf(S4[2][r], S4[3][r]));
            mv = fmaxf(mv, __shfl_xor(mv, 1, 16));
            mv = fmaxf(mv, __shfl_xor(mv, 2, 16));
            mv = fmaxf(mv, __shfl_xor(mv, 4, 16));
            mv = fmaxf(mv, __shfl_xor(mv, 8, 16));
            float nM = fmaxf(M[r], mv);
            float alpha = __expf(M[r] - nM);
            M[r] = nM;
            float rs = 0.f;
            #pragma unroll
            for (int ni = 0; ni < 4; ++ni) {
                float p = __expf(S4[ni][r] - nM);
                S4[ni][r] = p;
                rs += p;
            }
            rs += __shfl_xor(rs, 1, 16);
            rs += __shfl_xor(rs, 2, 16);
            rs += __shfl_xor(rs, 4, 16);
            rs += __shfl_xor(rs, 8, 16);
            L[r] = L[r] * alpha + rs;
            #pragma unroll
            for (int ni = 0; ni < 4; ++ni) O4[ni][r] *= alpha;
        }

        // --- P -> LDS fp16 hi/lo (same-wave region) ---
        #pragma unroll
        for (int ni = 0; ni < 4; ++ni) {
            #pragma unroll
            for (int r = 0; r < 4; ++r) {
                int row = wave * 16 + quad * 4 + r;
                int col = ni * 16 + l15;
                unsigned short h, l;
                splith(S4[ni][r], h, l);
                PH[row * 72 + col] = h;
                PL[row * 72 + col] = l;
            }
        }

        // --- P @ W (fp16 hi/lo, 3 products) ---
        __builtin_amdgcn_s_setprio(1);
        #pragma unroll
        for (int ks = 0; ks < 2; ++ks) {
            hfrag aph = *(const hfrag*)&PH[(wave * 16 + l15) * 72 + ks * 32 + quad * 8];
            hfrag apl = *(const hfrag*)&PL[(wave * 16 + l15) * 72 + ks * 32 + quad * 8];
            #pragma unroll
            for (int ni = 0; ni < 4; ++ni) {
                hfrag bwh = *(const hfrag*)&WH[(ni * 16 + l15) * 72 + ks * 32 + quad * 8];
                hfrag bwl = *(const hfrag*)&WL[(ni * 16 + l15) * 72 + ks * 32 + quad * 8];
                O4[ni] = __builtin_amdgcn_mfma_f32_16x16x32_f16(apl, bwh, O4[ni], 0, 0, 0);
                O4[ni] = __builtin_amdgcn_mfma_f32_16x16x32_f16(aph, bwl, O4[ni], 0, 0, 0);
                O4[ni] = __builtin_amdgcn_mfma_f32_16x16x32_f16(aph, bwh, O4[ni], 0, 0, 0);
            }
        }
        __builtin_amdgcn_s_setprio(0);
    }

    // direct store: out[row][d] = O * (64/L)
    float inv[4];
    #pragma unroll
    for (int r = 0; r < 4; ++r) inv[r] = 64.0f / L[r];
    #pragma unroll
    for (int r = 0; r < 4; ++r) {
        int row = wave * 16 + quad * 4 + r;
        float* dst = out + ((size_t)bh * N_SEQ + r0 + row) * DHEAD;
        #pragma unroll
        for (int ni = 0; ni < 4; ++ni)
            dst[ni * 16 + l15] = O4[ni][r] * inv[r];
    }
}

// ---------------------------------------------------------------------------
// 7) out += conv33(v). (round 7-verified, unchanged)
// ---------------------------------------------------------------------------
__global__ __launch_bounds__(256) void k_conv_add(
    const float* __restrict__ v, const float* __restrict__ cw,
    float* __restrict__ out)
{
    __shared__ __align__(16) float smem[160 * 68];
    __shared__ float wgt[33];
    int bh = blockIdx.y;
    int r0 = blockIdx.x * 128;
    int t = threadIdx.x;
    int wave = t >> 6, lane = t & 63;
    int ly = lane >> 3, lx = lane & 7;
    int rb = wave * 32 + ly * 4;

    if (t < 33) wgt[t] = cw[(bh & 7) * 33 + t];

    for (int rr = t; rr < 160; rr += 256) {
        int gr = r0 - 16 + rr;
        bool ok = (gr >= 0) && (gr < N_SEQ);
        const float* src = v + ((size_t)bh * N_SEQ + gr) * DHEAD;
        #pragma unroll
        for (int c = 0; c < 64; c += 4) {
            float4 val = ok ? *(const float4*)(src + c) : make_float4(0.f, 0.f, 0.f, 0.f);
            *(float4*)&smem[rr * 68 + c] = val;
        }
    }
    __syncthreads();

    float res[4][8] = {};
    #pragma unroll
    for (int w = 0; w < 36; ++w) {
        float4 va  = *(const float4*)&smem[(rb + w) * 68 + lx * 8];
        float4 vb4 = *(const float4*)&smem[(rb + w) * 68 + lx * 8 + 4];
        #pragma unroll
        for (int i = 0; i < 4; ++i) {
            if (w - i >= 0 && w - i <= 32) {
                float wv = wgt[w - i];
                fma8(res[i], wv, va, vb4);
            }
        }
    }

    #pragma unroll
    for (int i = 0; i < 4; ++i) {
        float* dst = out + ((size_t)bh * N_SEQ + r0 + rb + i) * DHEAD + lx * 8;
        float4 o0 = *(const float4*)dst;
        float4 o1 = *(const float4*)(dst + 4);
        *(float4*)dst = make_float4(o0.x + res[i][0], o0.y + res[i][1],
                                    o0.z + res[i][2], o0.w + res[i][3]);
        *(float4*)(dst + 4) = make_float4(o1.x + res[i][4], o1.y + res[i][5],
                                          o1.z + res[i][6], o1.w + res[i][7]);
    }
}

// ---------------------------------------------------------------------------
// launch
// ---------------------------------------------------------------------------
extern "C" void kernel_launch(void* const* d_in, const int* in_sizes, int n_in,
                              void* d_out, int out_size, void* d_ws, size_t ws_size,
                              hipStream_t stream)
{
    (void)in_sizes; (void)n_in; (void)out_size; (void)ws_size;
    const float* q  = (const float*)d_in[0];
    const float* k  = (const float*)d_in[1];
    const float* v  = (const float*)d_in[2];
    const float* cw = (const float*)d_in[3];
    float* out = (float*)d_out;
    float* ws  = (float*)d_ws;

    const size_t LM = (size_t)LM_E;   // 262144 floats
    const size_t MM = (size_t)MM_E;   // 1048576 floats

    // float-unit layout (total ~29.6 MB, <= proven 29.9 MB):
    float* ql  = ws;                  // LM
    float* kl  = ql  + LM;            // LM
    float* xsf = kl  + LM;            // MM floats  = xh|xl planes (2*MM ushorts)
    float* zsf = xsf + MM;            // MM floats  = zh|zl planes
    float* big = zsf + MM;            // 4*MM floats: pO (2*MM fl) then 8 planes
    float* kvf = big + 4 * MM;        // LM floats  = kvh|kvl planes
    float* W   = kvf + LM;            // LM floats
    float* scl = W   + LM;            // 16
    float* pm  = scl + 16;            // NBH*NSPLIT3*MLAND
    float* pl  = pm + (size_t)NBH * NSPLIT3 * MLAND;

    float* pO = big;                  // 2*MM floats, dead before pinv chain

    unsigned short* xs  = (unsigned short*)xsf;
    unsigned short* zs  = (unsigned short*)zsf;
    unsigned short* bgu = (unsigned short*)big;   // 8*MM ushorts
    unsigned short* kvs = (unsigned short*)kvf;

    unsigned short* xh  = xs;
    unsigned short* xl  = xs + MM;
    unsigned short* zh  = zs;
    unsigned short* zl  = zs + MM;
    unsigned short* z2h = bgu;
    unsigned short* z2l = bgu + MM;
    unsigned short* xzh = bgu + 2 * MM;
    unsigned short* xzl = bgu + 3 * MM;
    unsigned short* t2h = bgu + 4 * MM;
    unsigned short* t2l = bgu + 5 * MM;
    unsigned short* t3h = bgu + 6 * MM;
    unsigned short* t3l = bgu + 7 * MM;
    unsigned short* kvh = kvs;
    unsigned short* kvl = kvs + LM;

    hipMemsetAsync(scl, 0, 32, stream);

    k_landmarks<<<dim3(NBH * MLAND, 2), 64, 0, stream>>>(q, k, ql, kl);
    k_sim2_softmax<<<NBH * MLAND, 256, 0, stream>>>(ql, kl, xs);
    k_scale_reduce<<<NBH, 256, 0, stream>>>(xs, scl);
    k_zinit<<<dim3(8, 8, NBH), 256, 0, stream>>>(xs, zs, scl);

    k_attn3_partial<<<dim3(NSPLIT3, 4, NBH), 256, 0, stream>>>(ql, k, v, pO, pm, pl);
    k_attn3_combine<<<NBH * MLAND, 64, 0, stream>>>(pO, pm, pl, kvs);

    // Moore-Penrose: z' = 0.25*z@(13I - xz@(15I - xz@(7I - xz))), xz = x@z
    // 32x64 tiles: grid (N/64, 256/32, NBH) = (4, 8, 16) = 512 blocks.
    unsigned short *zch = zh, *zcl = zl, *znh = z2h, *znl = z2l;
    for (int it = 0; it < 6; ++it) {
        k_bmm_planes<<<dim3(4, 8, NBH), 256, 0, stream>>>(
            xh, xl, zch, zcl, xzh, xzl, nullptr, 256, 0.f, 1.f, 1.f);
        k_bmm_planes<<<dim3(4, 8, NBH), 256, 0, stream>>>(
            xzh, xzl, xzh, xzl, t2h, t2l, nullptr, 256, 7.f, -1.f, 1.f);
        k_bmm_planes<<<dim3(4, 8, NBH), 256, 0, stream>>>(
            xzh, xzl, t2h, t2l, t3h, t3l, nullptr, 256, 15.f, -1.f, 1.f);
        k_bmm_planes<<<dim3(4, 8, NBH), 256, 0, stream>>>(
            zch, zcl, t3h, t3l, znh, znl, nullptr, 256, 13.f, -1.f, 0.25f);
        unsigned short* th = zch; zch = znh; znh = th;
        unsigned short* tl = zcl; zcl = znl; znl = tl;
    }
    // W = attn2_inv @ kv   [256x256 @ 256x64], fp32 out
    k_bmm_planes<<<dim3(1, 8, NBH), 256, 0, stream>>>(
        zch, zcl, kvh, kvl, nullptr, nullptr, W, 64, 0.f, 1.f, 1.f);

    k_attn1_mfma<<<dim3(128, NBH), 256, 0, stream>>>(q, kl, W, out);
    k_conv_add<<<dim3(64, NBH), 256, 0, stream>>>(v, cw, out);
}

// Round 8
// 568.084 us; speedup vs baseline: 3.6202x; 1.0572x over previous
//
#include <hip/hip_runtime.h>

// ---------------------------------------------------------------------------
// Nystrom attention, fp32. b=2,h=8,n=8192,d=64, m=256 landmarks, conv33.
// Round 15: (1) pinv chain bmm gets bh-pinned XCD swizzle (all tiles of bh b
// on XCD b%8 -> cross-step L2 residency, ~3MB/XCD working set). (2)
// k_scale_reduce parallelized 16 -> 256 blocks. Rest = round 14 (600.6us).
// ---------------------------------------------------------------------------

#define N_SEQ 8192
#define NBH   16
#define MLAND 256
#define DHEAD 64
#define NSPLIT3 8
#define MM_E  (NBH * MLAND * MLAND)   // 1048576 elements per plane
#define LM_E  (NBH * MLAND * DHEAD)   // 262144

typedef __attribute__((ext_vector_type(8))) short bfrag;
typedef __attribute__((ext_vector_type(8))) _Float16 hfrag;
typedef __attribute__((ext_vector_type(4))) float f32x4;

__device__ __forceinline__ void fma8(float (&o)[8], float p, const float4& a, const float4& b) {
    o[0] += p * a.x; o[1] += p * a.y; o[2] += p * a.z; o[3] += p * a.w;
    o[4] += p * b.x; o[5] += p * b.y; o[6] += p * b.z; o[7] += p * b.w;
}

__device__ __forceinline__ float bf2f(unsigned short h) {
    return __uint_as_float(((unsigned)h) << 16);
}

// truncation hi/lo split (bf16): hi = top 16 bits, lo = bf16(v - hi).
__device__ __forceinline__ void splitbf(float v, unsigned short& h, unsigned short& l) {
    unsigned bits = __float_as_uint(v);
    h = (unsigned short)(bits >> 16);
    float r = v - __uint_as_float(bits & 0xffff0000u);
    l = (unsigned short)(__float_as_uint(r) >> 16);
}

// fp16 hi/lo split: ~22 mantissa bits total. h = rn(v), l = rn(v - h).
__device__ __forceinline__ void splith(float v, unsigned short& h, unsigned short& l) {
    _Float16 hf = (_Float16)v;
    _Float16 lf = (_Float16)(v - (float)hf);
    h = __builtin_bit_cast(unsigned short, hf);
    l = __builtin_bit_cast(unsigned short, lf);
}

// read 16 consecutive floats, write hi/lo ushorts u32-packed (bf16 version)
__device__ __forceinline__ void stage16(const float* __restrict__ src,
                                        unsigned short* dh, unsigned short* dl) {
    unsigned* ph = (unsigned*)dh;
    unsigned* pl = (unsigned*)dl;
    #pragma unroll
    for (int o = 0; o < 16; o += 4) {
        float4 a = *(const float4*)(src + o);
        float vv[4] = {a.x, a.y, a.z, a.w};
        unsigned short h[4], l[4];
        #pragma unroll
        for (int u = 0; u < 4; ++u) splitbf(vv[u], h[u], l[u]);
        ph[o / 2]     = (unsigned)h[0] | ((unsigned)h[1] << 16);
        ph[o / 2 + 1] = (unsigned)h[2] | ((unsigned)h[3] << 16);
        pl[o / 2]     = (unsigned)l[0] | ((unsigned)l[1] << 16);
        pl[o / 2 + 1] = (unsigned)l[2] | ((unsigned)l[3] << 16);
    }
}

// fp16 version of stage16
__device__ __forceinline__ void stageh16(const float* __restrict__ src,
                                         unsigned short* dh, unsigned short* dl) {
    unsigned* ph = (unsigned*)dh;
    unsigned* pl = (unsigned*)dl;
    #pragma unroll
    for (int o = 0; o < 16; o += 4) {
        float4 a = *(const float4*)(src + o);
        float vv[4] = {a.x, a.y, a.z, a.w};
        unsigned short h[4], l[4];
        #pragma unroll
        for (int u = 0; u < 4; ++u) splith(vv[u], h[u], l[u]);
        ph[o / 2]     = (unsigned)h[0] | ((unsigned)h[1] << 16);
        ph[o / 2 + 1] = (unsigned)h[2] | ((unsigned)h[3] << 16);
        pl[o / 2]     = (unsigned)l[0] | ((unsigned)l[1] << 16);
        pl[o / 2 + 1] = (unsigned)l[2] | ((unsigned)l[3] << 16);
    }
}

// ---------------------------------------------------------------------------
// 1) landmark means
// ---------------------------------------------------------------------------
__global__ __launch_bounds__(64) void k_landmarks(
    const float* __restrict__ q, const float* __restrict__ k,
    float* __restrict__ ql, float* __restrict__ kl)
{
    int mi = blockIdx.x & 255;
    int bh = blockIdx.x >> 8;
    const float* src = blockIdx.y ? k : q;
    float*       dst = blockIdx.y ? kl : ql;
    int t = threadIdx.x;
    const float* s = src + ((size_t)bh * N_SEQ + (size_t)mi * 32) * DHEAD;
    float acc = 0.f;
    #pragma unroll
    for (int j = 0; j < 32; ++j) acc += s[j * DHEAD + t];
    dst[((size_t)bh * MLAND + mi) * DHEAD + t] = acc * (1.f / 32.f);
}

// ---------------------------------------------------------------------------
// 2) attn2 = softmax(ql @ kl^T) rowwise -> split bf16 planes (xh|xl)
// ---------------------------------------------------------------------------
__global__ __launch_bounds__(256) void k_sim2_softmax(
    const float* __restrict__ ql, const float* __restrict__ kl,
    unsigned short* __restrict__ xs)
{
    unsigned short* xh = xs;
    unsigned short* xl = xs + MM_E;
    int bh = blockIdx.x >> 8;
    int i  = blockIdx.x & 255;
    int t  = threadIdx.x;
    __shared__ float qrow[DHEAD];
    __shared__ float wred[8];
    if (t < DHEAD) qrow[t] = ql[((size_t)bh * MLAND + i) * DHEAD + t];
    __syncthreads();
    const float* krow = kl + ((size_t)bh * MLAND + t) * DHEAD;
    float s = 0.f;
    #pragma unroll
    for (int kk = 0; kk < DHEAD; kk += 4) {
        float4 k4 = *(const float4*)(krow + kk);
        s += qrow[kk] * k4.x + qrow[kk + 1] * k4.y + qrow[kk + 2] * k4.z + qrow[kk + 3] * k4.w;
    }
    float m = s;
    #pragma unroll
    for (int o = 32; o > 0; o >>= 1) m = fmaxf(m, __shfl_xor(m, o, 64));
    int wave = t >> 6, lane = t & 63;
    if (lane == 0) wred[wave] = m;
    __syncthreads();
    float bm = fmaxf(fmaxf(wred[0], wred[1]), fmaxf(wred[2], wred[3]));
    float e = __expf(s - bm);
    float sum = e;
    #pragma unroll
    for (int o = 32; o > 0; o >>= 1) sum += __shfl_xor(sum, o, 64);
    if (lane == 0) wred[4 + wave] = sum;
    __syncthreads();
    float bs = wred[4] + wred[5] + wred[6] + wred[7];
    float val = e / bs;
    unsigned short h, l;
    splitbf(val, h, l);
    size_t idx = ((size_t)bh * MLAND + i) * MLAND + t;
    xh[idx] = h;
    xl[idx] = l;
}

// ---------------------------------------------------------------------------
// 3a) global max of row-sums and col-sums of attn2 (from planes).
//     Round 15: 256 blocks (bh x 16 segs), coalesced segment partials.
// ---------------------------------------------------------------------------
__global__ __launch_bounds__(256) void k_scale_reduce(
    const unsigned short* __restrict__ xs, float* __restrict__ scl)
{
    const unsigned short* xh = xs;
    const unsigned short* xl = xs + MM_E;
    int bh = blockIdx.y, seg = blockIdx.x;
    int t = threadIdx.x;
    size_t b = (size_t)bh * MLAND * MLAND;
    __shared__ float red[32];
    __shared__ float red2[256];

    // rowsum: rows seg*16..+16; thread t: row seg*16+(t>>4), j-seg (t&15)*16
    {
        int r = seg * 16 + (t >> 4);
        int j0 = (t & 15) * 16;
        float rp = 0.f;
        #pragma unroll
        for (int j = 0; j < 16; ++j) {
            size_t idx = b + (size_t)r * MLAND + j0 + j;
            rp += bf2f(xh[idx]) + bf2f(xl[idx]);
        }
        rp += __shfl_xor(rp, 1, 16);
        rp += __shfl_xor(rp, 2, 16);
        rp += __shfl_xor(rp, 4, 16);
        rp += __shfl_xor(rp, 8, 16);
        if ((t & 15) == 0) red[t >> 4] = rp;
        __syncthreads();
        if (t == 0) {
            float m = red[0];
            #pragma unroll
            for (int i = 1; i < 16; ++i) m = fmaxf(m, red[i]);
            atomicMax((unsigned int*)&scl[0], __float_as_uint(m));
        }
        __syncthreads();
    }
    // colsum: cols seg*16..+16; thread t: col seg*16+(t&15), i-seg (t>>4)*16
    {
        int c = seg * 16 + (t & 15);
        int i0 = (t >> 4) * 16;
        float cp = 0.f;
        #pragma unroll
        for (int i = 0; i < 16; ++i) {
            size_t idx = b + (size_t)(i0 + i) * MLAND + c;
            cp += bf2f(xh[idx]) + bf2f(xl[idx]);
        }
        red2[t] = cp;
        __syncthreads();
        if (t < 16) {
            float s = 0.f;
            #pragma unroll
            for (int g = 0; g < 16; ++g) s += red2[g * 16 + t];
            red[t] = s;
        }
        __syncthreads();
        if (t == 0) {
            float m = red[0];
            #pragma unroll
            for (int i = 1; i < 16; ++i) m = fmaxf(m, red[i]);
            atomicMax((unsigned int*)&scl[1], __float_as_uint(m));
        }
    }
}

// ---------------------------------------------------------------------------
// 3b) z0 = attn2^T / (scl[0]*scl[1])  (planes -> planes)
// ---------------------------------------------------------------------------
__global__ __launch_bounds__(256) void k_zinit(
    const unsigned short* __restrict__ xs, unsigned short* __restrict__ zs,
    const float* __restrict__ scl)
{
    const unsigned short* xh = xs;
    const unsigned short* xl = xs + MM_E;
    unsigned short* zh = zs;
    unsigned short* zl = zs + MM_E;
    __shared__ float tile[32][33];
    int bh = blockIdx.z;
    int i0 = blockIdx.y * 32, j0 = blockIdx.x * 32;
    int t = threadIdx.x;
    int lx = t & 31, ly = t >> 5;
    size_t b = (size_t)bh * MLAND * MLAND;
    #pragma unroll
    for (int p = 0; p < 4; ++p) {
        size_t idx = b + (size_t)(i0 + ly + 8 * p) * MLAND + j0 + lx;
        tile[ly + 8 * p][lx] = bf2f(xh[idx]) + bf2f(xl[idx]);
    }
    __syncthreads();
    float inv = 1.0f / (scl[0] * scl[1]);
    #pragma unroll
    for (int p = 0; p < 4; ++p) {
        float val = tile[lx][ly + 8 * p] * inv;
        unsigned short h, l;
        splitbf(val, h, l);
        size_t idx = b + (size_t)(j0 + ly + 8 * p) * MLAND + i0 + lx;
        zh[idx] = h;
        zl[idx] = l;
    }
}

// ---------------------------------------------------------------------------
// 4) plane bmm: C = outscale * (A @ (diag*I + bscale*B)); M=K=256, N param.
//    Round 15: 1-D grid, bh-pinned XCD swizzle: bid&7 selects XCD (default
//    round-robin), bh = (bid&7) + 8*((bid>>3)&1) -> all tiles of bh b stay
//    on XCD b%8 across all 25 steps -> chain data stays in that XCD's L2.
//    Tile body unchanged from round 14 (verified).
// ---------------------------------------------------------------------------
__global__ __launch_bounds__(256) void k_bmm_planes(
    const unsigned short* __restrict__ Ahp, const unsigned short* __restrict__ Alp,
    const unsigned short* __restrict__ Bhp, const unsigned short* __restrict__ Blp,
    unsigned short* __restrict__ Chp, unsigned short* __restrict__ Clp,
    float* __restrict__ Cf,
    int N, float diag, float bscale, float outscale)
{
    __shared__ unsigned short sm[2 * 32 * 72 + 2 * 64 * 72];   // Ah|Al|Bh|Bl 27.6KB
    unsigned short* Ah = sm;
    unsigned short* Al = sm + 32 * 72;
    unsigned short* Bh = sm + 2 * 32 * 72;
    unsigned short* Bl = sm + 2 * 32 * 72 + 64 * 72;

    int ntn = N >> 6;                 // n-tiles (64 wide): 4 for N=256, 1 for N=64
    int bid = blockIdx.x;
    int xcd  = bid & 7;
    int slot = bid >> 3;
    int bh   = xcd + 8 * (slot & 1);
    int tile = slot >> 1;             // [0, 8*ntn)
    int m0 = (tile / ntn) * 32, n0 = (tile % ntn) * 64;

    const size_t abase = (size_t)bh * 65536;
    const size_t bbase = (size_t)bh * 256 * N;
    int t = threadIdx.x;
    int wave = t >> 6, lane = t & 63;
    int l15 = lane & 15, quad = lane >> 4;
    int wr = wave >> 1, wc = wave & 1;          // wave strip: rows wr*16, cols wc*32
    unsigned sflip = (bscale < 0.f) ? 0x8000u : 0u;

    f32x4 acc[2] = {};

    for (int kc = 0; kc < 256; kc += 64) {
        __syncthreads();
        {   // stage A rows natural [m][k], 32 rows: thread row m=t&31, 8 k's
            int m = t & 31, ks = (t >> 5) * 8;
            size_t off = abase + (size_t)(m0 + m) * 256 + kc + ks;
            *(uint4*)&Ah[m * 72 + ks] = *(const uint4*)&Ahp[off];
            *(uint4*)&Al[m * 72 + ks] = *(const uint4*)&Alp[off];
        }
        {   // stage B transposed [n][k]: vector load, sign-flip, scatter
            int kk = t & 63, ns = (t >> 6) * 16;
            int gk = kc + kk;
            size_t off = bbase + (size_t)gk * N + n0 + ns;
            unsigned short hb[16], lb[16];
            *(uint4*)&hb[0] = *(const uint4*)&Bhp[off];
            *(uint4*)&hb[8] = *(const uint4*)&Bhp[off + 8];
            *(uint4*)&lb[0] = *(const uint4*)&Blp[off];
            *(uint4*)&lb[8] = *(const uint4*)&Blp[off + 8];
            #pragma unroll
            for (int u = 0; u < 16; ++u) {
                unsigned short h = hb[u] ^ sflip;
                unsigned short l = lb[u] ^ sflip;
                if (diag != 0.f && gk == n0 + ns + u) {
                    float val = diag + bf2f(h) + bf2f(l);
                    splitbf(val, h, l);
                }
                Bh[(ns + u) * 72 + kk] = h;
                Bl[(ns + u) * 72 + kk] = l;
            }
        }
        __syncthreads();

        #pragma unroll
        for (int k0 = 0; k0 < 64; k0 += 32) {
            int kf = k0 + quad * 8;
            int am = wr * 16 + l15;
            bfrag ah = *(const bfrag*)&Ah[am * 72 + kf];
            bfrag al = *(const bfrag*)&Al[am * 72 + kf];
            #pragma unroll
            for (int j = 0; j < 2; ++j) {
                int bn = wc * 32 + j * 16 + l15;
                bfrag bhf = *(const bfrag*)&Bh[bn * 72 + kf];
                bfrag blf = *(const bfrag*)&Bl[bn * 72 + kf];
                acc[j] = __builtin_amdgcn_mfma_f32_16x16x32_bf16(al, bhf, acc[j], 0, 0, 0);
                acc[j] = __builtin_amdgcn_mfma_f32_16x16x32_bf16(ah, blf, acc[j], 0, 0, 0);
                acc[j] = __builtin_amdgcn_mfma_f32_16x16x32_bf16(ah, bhf, acc[j], 0, 0, 0);
            }
        }
    }

    size_t cbase = (size_t)bh * 256 * N;
    if (Cf) {
        #pragma unroll
        for (int j = 0; j < 2; ++j) {
            #pragma unroll
            for (int r = 0; r < 4; ++r) {
                int row = m0 + wr * 16 + quad * 4 + r;
                int col = n0 + wc * 32 + j * 16 + l15;
                Cf[cbase + (size_t)row * N + col] = acc[j][r] * outscale;
            }
        }
    } else {
        #pragma unroll
        for (int j = 0; j < 2; ++j) {
            #pragma unroll
            for (int r = 0; r < 4; ++r) {
                int row = m0 + wr * 16 + quad * 4 + r;
                int col = n0 + wc * 32 + j * 16 + l15;
                float val = acc[j][r] * outscale;
                unsigned short h, l;
                splitbf(val, h, l);
                size_t idx = cbase + (size_t)row * N + col;
                Chp[idx] = h;
                Clp[idx] = l;
            }
        }
    }
}

// ---------------------------------------------------------------------------
// 5a) attn3 flash partial, MFMA bf16 hi/lo split. (round 8, unchanged)
// ---------------------------------------------------------------------------
__global__ __launch_bounds__(256, 2) void k_attn3_partial(
    const float* __restrict__ ql, const float* __restrict__ k,
    const float* __restrict__ v, float* __restrict__ pO,
    float* __restrict__ pm, float* __restrict__ pl)
{
    __shared__ __align__(16) unsigned short sm3[36864];
    unsigned short* QH = sm3;
    unsigned short* QL = sm3 + 4608;
    unsigned short* KH = sm3 + 9216;
    unsigned short* KL = sm3 + 13824;
    unsigned short* VH = sm3 + 18432;
    unsigned short* VL = sm3 + 23040;
    unsigned short* PH = sm3 + 27648;
    unsigned short* PL = sm3 + 32256;

    int sp = blockIdx.x;              // 0..7, 1024 keys each
    int m0 = blockIdx.y * 64;         // landmark rows
    int bh = blockIdx.z;
    int t = threadIdx.x;
    int wave = t >> 6, lane = t & 63;
    int l15 = lane & 15, quad = lane >> 4;

    {   // stage Q once: 64 rows x 64 d, natural [m][d]
        int row = t & 63, ds = (t >> 6) * 16;
        const float* src = ql + ((size_t)bh * MLAND + m0 + row) * DHEAD + ds;
        stage16(src, &QH[row * 72 + ds], &QL[row * 72 + ds]);
    }
    __syncthreads();

    bfrag aqh[2], aql[2];
    #pragma unroll
    for (int ks = 0; ks < 2; ++ks) {
        aqh[ks] = *(const bfrag*)&QH[(wave * 16 + l15) * 72 + ks * 32 + quad * 8];
        aql[ks] = *(const bfrag*)&QL[(wave * 16 + l15) * 72 + ks * 32 + quad * 8];
    }

    f32x4 O[4] = {};                  // d-tile ni; lane holds rows quad*4+r
    float M[4], L[4];
    #pragma unroll
    for (int r = 0; r < 4; ++r) { M[r] = -1e30f; L[r] = 0.f; }

    const float* kb = k + (size_t)bh * N_SEQ * DHEAD;
    const float* vb = v + (size_t)bh * N_SEQ * DHEAD;

    for (int cc = 0; cc < 16; ++cc) {
        int c0 = sp * 1024 + cc * 64;
        __syncthreads();              // prev chunk's K/V reads done
        {   // K natural [key][d]
            int key = t & 63, ds = (t >> 6) * 16;
            stage16(kb + (size_t)(c0 + key) * DHEAD + ds,
                    &KH[key * 72 + ds], &KL[key * 72 + ds]);
        }
        {   // V transposed [d][key]
            int key = t & 63, dq = (t >> 6) * 16;
            const float* src = vb + (size_t)(c0 + key) * DHEAD + dq;
            #pragma unroll
            for (int o = 0; o < 16; o += 4) {
                float4 a = *(const float4*)(src + o);
                float vv[4] = {a.x, a.y, a.z, a.w};
                #pragma unroll
                for (int u = 0; u < 4; ++u) {
                    unsigned short h, l;
                    splitbf(vv[u], h, l);
                    VH[(dq + o + u) * 72 + key] = h;
                    VL[(dq + o + u) * 72 + key] = l;
                }
            }
        }
        __syncthreads();

        // --- QK^T ---
        f32x4 S4[4] = {};
        __builtin_amdgcn_s_setprio(1);
        #pragma unroll
        for (int ks = 0; ks < 2; ++ks) {
            #pragma unroll
            for (int ni = 0; ni < 4; ++ni) {
                bfrag bkh = *(const bfrag*)&KH[(ni * 16 + l15) * 72 + ks * 32 + quad * 8];
                bfrag bkl = *(const bfrag*)&KL[(ni * 16 + l15) * 72 + ks * 32 + quad * 8];
                S4[ni] = __builtin_amdgcn_mfma_f32_16x16x32_bf16(aql[ks], bkh, S4[ni], 0, 0, 0);
                S4[ni] = __builtin_amdgcn_mfma_f32_16x16x32_bf16(aqh[ks], bkl, S4[ni], 0, 0, 0);
                S4[ni] = __builtin_amdgcn_mfma_f32_16x16x32_bf16(aqh[ks], bkh, S4[ni], 0, 0, 0);
            }
        }
        __builtin_amdgcn_s_setprio(0);

        // --- online softmax ---
        #pragma unroll
        for (int r = 0; r < 4; ++r) {
            float mv = fmaxf(fmaxf(S4[0][r], S4[1][r]), fmaxf(S4[2][r], S4[3][r]));
            mv = fmaxf(mv, __shfl_xor(mv, 1, 16));
            mv = fmaxf(mv, __shfl_xor(mv, 2, 16));
            mv = fmaxf(mv, __shfl_xor(mv, 4, 16));
            mv = fmaxf(mv, __shfl_xor(mv, 8, 16));
            float nM = fmaxf(M[r], mv);
            float alpha = __expf(M[r] - nM);
            M[r] = nM;
            float rs = 0.f;
            #pragma unroll
            for (int ni = 0; ni < 4; ++ni) {
                float p = __expf(S4[ni][r] - nM);
                S4[ni][r] = p;
                rs += p;
            }
            rs += __shfl_xor(rs, 1, 16);
            rs += __shfl_xor(rs, 2, 16);
            rs += __shfl_xor(rs, 4, 16);
            rs += __shfl_xor(rs, 8, 16);
            L[r] = L[r] * alpha + rs;
            #pragma unroll
            for (int ni = 0; ni < 4; ++ni) O[ni][r] *= alpha;
        }

        // --- P -> LDS hi/lo (same-wave region) ---
        #pragma unroll
        for (int ni = 0; ni < 4; ++ni) {
            #pragma unroll
            for (int r = 0; r < 4; ++r) {
                int row = wave * 16 + quad * 4 + r;
                int col = ni * 16 + l15;
                unsigned short h, l;
                splitbf(S4[ni][r], h, l);
                PH[row * 72 + col] = h;
                PL[row * 72 + col] = l;
            }
        }

        // --- PV ---
        __builtin_amdgcn_s_setprio(1);
        #pragma unroll
        for (int ks = 0; ks < 2; ++ks) {
            bfrag aph = *(const bfrag*)&PH[(wave * 16 + l15) * 72 + ks * 32 + quad * 8];
            bfrag apl = *(const bfrag*)&PL[(wave * 16 + l15) * 72 + ks * 32 + quad * 8];
            #pragma unroll
            for (int ni = 0; ni < 4; ++ni) {
                bfrag bvh = *(const bfrag*)&VH[(ni * 16 + l15) * 72 + ks * 32 + quad * 8];
                bfrag bvl = *(const bfrag*)&VL[(ni * 16 + l15) * 72 + ks * 32 + quad * 8];
                O[ni] = __builtin_amdgcn_mfma_f32_16x16x32_bf16(apl, bvh, O[ni], 0, 0, 0);
                O[ni] = __builtin_amdgcn_mfma_f32_16x16x32_bf16(aph, bvl, O[ni], 0, 0, 0);
                O[ni] = __builtin_amdgcn_mfma_f32_16x16x32_bf16(aph, bvh, O[ni], 0, 0, 0);
            }
        }
        __builtin_amdgcn_s_setprio(0);
    }

    int base = (bh * NSPLIT3 + sp) * MLAND + m0;
    #pragma unroll
    for (int r = 0; r < 4; ++r) {
        int row = wave * 16 + quad * 4 + r;
        if (l15 == 0) { pm[base + row] = M[r]; pl[base + row] = L[r]; }
        #pragma unroll
        for (int ni = 0; ni < 4; ++ni)
            pO[(size_t)(base + row) * DHEAD + ni * 16 + l15] = O[ni][r];
    }
}

// ---------------------------------------------------------------------------
// 5b) combine 8 splits -> kv planes (split bf16)
// ---------------------------------------------------------------------------
__global__ __launch_bounds__(64) void k_attn3_combine(
    const float* __restrict__ pO, const float* __restrict__ pm,
    const float* __restrict__ pl, unsigned short* __restrict__ kvs)
{
    unsigned short* kvh = kvs;
    unsigned short* kvl = kvs + LM_E;
    int bh = blockIdx.x >> 8;
    int m  = blockIdx.x & 255;
    int d  = threadIdx.x;
    float M = -1e30f;
    #pragma unroll
    for (int s = 0; s < NSPLIT3; ++s) M = fmaxf(M, pm[(bh * NSPLIT3 + s) * MLAND + m]);
    float L = 0.f, O = 0.f;
    #pragma unroll
    for (int s = 0; s < NSPLIT3; ++s) {
        int base = (bh * NSPLIT3 + s) * MLAND + m;
        float w = __expf(pm[base] - M);
        L += pl[base] * w;
        O += w * pO[(size_t)base * DHEAD + d];
    }
    float val = O / L;
    unsigned short h, l;
    splitbf(val, h, l);
    size_t idx = ((size_t)bh * MLAND + m) * DHEAD + d;
    kvh[idx] = h;
    kvl[idx] = l;
}

// ---------------------------------------------------------------------------
// 6) out = softmax(q @ kl^T) @ W, MFMA fp16 hi/lo split. (round 11, unchanged)
// ---------------------------------------------------------------------------
__global__ __launch_bounds__(256, 2) void k_attn1_mfma(
    const float* __restrict__ q, const float* __restrict__ kl,
    const float* __restrict__ W, float* __restrict__ out)
{
    __shared__ __align__(16) unsigned short sm1[36864];
    unsigned short* QH = sm1;
    unsigned short* QL = sm1 + 4608;
    unsigned short* KH = sm1 + 9216;
    unsigned short* KL = sm1 + 13824;
    unsigned short* WH = sm1 + 18432;
    unsigned short* WL = sm1 + 23040;
    unsigned short* PH = sm1 + 27648;
    unsigned short* PL = sm1 + 32256;

    int bh = blockIdx.y;
    int r0 = blockIdx.x * 64;
    int t = threadIdx.x;
    int wave = t >> 6, lane = t & 63;
    int l15 = lane & 15, quad = lane >> 4;

    {   // stage Q once: 64 rows x 64 d, natural [m][d], fp16 hi/lo
        int row = t & 63, ds = (t >> 6) * 16;
        const float* src = q + ((size_t)bh * N_SEQ + r0 + row) * DHEAD + ds;
        stageh16(src, &QH[row * 72 + ds], &QL[row * 72 + ds]);
    }
    __syncthreads();

    hfrag aqh[2], aql[2];
    #pragma unroll
    for (int ks = 0; ks < 2; ++ks) {
        aqh[ks] = *(const hfrag*)&QH[(wave * 16 + l15) * 72 + ks * 32 + quad * 8];
        aql[ks] = *(const hfrag*)&QL[(wave * 16 + l15) * 72 + ks * 32 + quad * 8];
    }

    f32x4 O4[4] = {};                 // d-tile ni; lane holds rows quad*4+r
    float M[4], L[4];
    #pragma unroll
    for (int r = 0; r < 4; ++r) { M[r] = -1e30f; L[r] = 0.f; }

    for (int mc = 0; mc < 4; ++mc) {
        __syncthreads();              // prev chunk's KL/W reads done
        {   // kl chunk natural [land][d], fp16 hi/lo
            int key = t & 63, ds = (t >> 6) * 16;
            stageh16(kl + ((size_t)bh * MLAND + mc * 64 + key) * DHEAD + ds,
                     &KH[key * 72 + ds], &KL[key * 72 + ds]);
        }
        {   // W chunk transposed [d][land], scaled 1/64, fp16 hi/lo
            int key = t & 63, dq = (t >> 6) * 16;
            const float* src = W + ((size_t)bh * MLAND + mc * 64 + key) * DHEAD + dq;
            #pragma unroll
            for (int o = 0; o < 16; o += 4) {
                float4 a = *(const float4*)(src + o);
                float vv[4] = {a.x * 0.015625f, a.y * 0.015625f,
                               a.z * 0.015625f, a.w * 0.015625f};
                #pragma unroll
                for (int u = 0; u < 4; ++u) {
                    unsigned short h, l;
                    splith(vv[u], h, l);
                    WH[(dq + o + u) * 72 + key] = h;
                    WL[(dq + o + u) * 72 + key] = l;
                }
            }
        }
        __syncthreads();

        // --- q @ kl^T (fp16 hi/lo, 3 products) ---
        f32x4 S4[4] = {};
        __builtin_amdgcn_s_setprio(1);
        #pragma unroll
        for (int ks = 0; ks < 2; ++ks) {
            #pragma unroll
            for (int ni = 0; ni < 4; ++ni) {
                hfrag bkh = *(const hfrag*)&KH[(ni * 16 + l15) * 72 + ks * 32 + quad * 8];
                hfrag bkl = *(const hfrag*)&KL[(ni * 16 + l15) * 72 + ks * 32 + quad * 8];
                S4[ni] = __builtin_amdgcn_mfma_f32_16x16x32_f16(aql[ks], bkh, S4[ni], 0, 0, 0);
                S4[ni] = __builtin_amdgcn_mfma_f32_16x16x32_f16(aqh[ks], bkl, S4[ni], 0, 0, 0);
                S4[ni] = __builtin_amdgcn_mfma_f32_16x16x32_f16(aqh[ks], bkh, S4[ni], 0, 0, 0);
            }
        }
        __builtin_amdgcn_s_setprio(0);

        // --- online softmax (16-lane row groups) ---
        #pragma unroll
        for (int r = 0; r < 4; ++r) {
            float mv = fmaxf(fmaxf(S4[0][r], S4[1][r]), fmaxf(S4[2][r], S4[3][r]));
            mv = fmaxf(mv, __shfl_xor(mv, 1, 16));
            mv = fmaxf(mv, __shfl_xor(mv, 2, 16));
            mv = fmaxf(mv, __shfl_xor(mv, 4, 16));
            mv = fmaxf(mv, __shfl_xor(mv, 8, 16));
            float nM = fmaxf(M[r], mv);
            float alpha = __expf(M[r] - nM);
            M[r] = nM;
            float rs = 0.f;
            #pragma unroll
            for (int ni = 0; ni < 4; ++ni) {
                float p = __expf(S4[ni][r] - nM);
                S4[ni][r] = p;
                rs += p;
            }
            rs += __shfl_xor(rs, 1, 16);
            rs += __shfl_xor(rs, 2, 16);
            rs += __shfl_xor(rs, 4, 16);
            rs += __shfl_xor(rs, 8, 16);
            L[r] = L[r] * alpha + rs;
            #pragma unroll
            for (int ni = 0; ni < 4; ++ni) O4[ni][r] *= alpha;
        }

        // --- P -> LDS fp16 hi/lo (same-wave region) ---
        #pragma unroll
        for (int ni = 0; ni < 4; ++ni) {
            #pragma unroll
            for (int r = 0; r < 4; ++r) {
                int row = wave * 16 + quad * 4 + r;
                int col = ni * 16 + l15;
                unsigned short h, l;
                splith(S4[ni][r], h, l);
                PH[row * 72 + col] = h;
                PL[row * 72 + col] = l;
            }
        }

        // --- P @ W (fp16 hi/lo, 3 products) ---
        __builtin_amdgcn_s_setprio(1);
        #pragma unroll
        for (int ks = 0; ks < 2; ++ks) {
            hfrag aph = *(const hfrag*)&PH[(wave * 16 + l15) * 72 + ks * 32 + quad * 8];
            hfrag apl = *(const hfrag*)&PL[(wave * 16 + l15) * 72 + ks * 32 + quad * 8];
            #pragma unroll
            for (int ni = 0; ni < 4; ++ni) {
                hfrag bwh = *(const hfrag*)&WH[(ni * 16 + l15) * 72 + ks * 32 + quad * 8];
                hfrag bwl = *(const hfrag*)&WL[(ni * 16 + l15) * 72 + ks * 32 + quad * 8];
                O4[ni] = __builtin_amdgcn_mfma_f32_16x16x32_f16(apl, bwh, O4[ni], 0, 0, 0);
                O4[ni] = __builtin_amdgcn_mfma_f32_16x16x32_f16(aph, bwl, O4[ni], 0, 0, 0);
                O4[ni] = __builtin_amdgcn_mfma_f32_16x16x32_f16(aph, bwh, O4[ni], 0, 0, 0);
            }
        }
        __builtin_amdgcn_s_setprio(0);
    }

    // direct store: out[row][d] = O * (64/L)
    float inv[4];
    #pragma unroll
    for (int r = 0; r < 4; ++r) inv[r] = 64.0f / L[r];
    #pragma unroll
    for (int r = 0; r < 4; ++r) {
        int row = wave * 16 + quad * 4 + r;
        float* dst = out + ((size_t)bh * N_SEQ + r0 + row) * DHEAD;
        #pragma unroll
        for (int ni = 0; ni < 4; ++ni)
            dst[ni * 16 + l15] = O4[ni][r] * inv[r];
    }
}

// ---------------------------------------------------------------------------
// 7) out += conv33(v). (round 7-verified, unchanged)
// ---------------------------------------------------------------------------
__global__ __launch_bounds__(256) void k_conv_add(
    const float* __restrict__ v, const float* __restrict__ cw,
    float* __restrict__ out)
{
    __shared__ __align__(16) float smem[160 * 68];
    __shared__ float wgt[33];
    int bh = blockIdx.y;
    int r0 = blockIdx.x * 128;
    int t = threadIdx.x;
    int wave = t >> 6, lane = t & 63;
    int ly = lane >> 3, lx = lane & 7;
    int rb = wave * 32 + ly * 4;

    if (t < 33) wgt[t] = cw[(bh & 7) * 33 + t];

    for (int rr = t; rr < 160; rr += 256) {
        int gr = r0 - 16 + rr;
        bool ok = (gr >= 0) && (gr < N_SEQ);
        const float* src = v + ((size_t)bh * N_SEQ + gr) * DHEAD;
        #pragma unroll
        for (int c = 0; c < 64; c += 4) {
            float4 val = ok ? *(const float4*)(src + c) : make_float4(0.f, 0.f, 0.f, 0.f);
            *(float4*)&smem[rr * 68 + c] = val;
        }
    }
    __syncthreads();

    float res[4][8] = {};
    #pragma unroll
    for (int w = 0; w < 36; ++w) {
        float4 va  = *(const float4*)&smem[(rb + w) * 68 + lx * 8];
        float4 vb4 = *(const float4*)&smem[(rb + w) * 68 + lx * 8 + 4];
        #pragma unroll
        for (int i = 0; i < 4; ++i) {
            if (w - i >= 0 && w - i <= 32) {
                float wv = wgt[w - i];
                fma8(res[i], wv, va, vb4);
            }
        }
    }

    #pragma unroll
    for (int i = 0; i < 4; ++i) {
        float* dst = out + ((size_t)bh * N_SEQ + r0 + rb + i) * DHEAD + lx * 8;
        float4 o0 = *(const float4*)dst;
        float4 o1 = *(const float4*)(dst + 4);
        *(float4*)dst = make_float4(o0.x + res[i][0], o0.y + res[i][1],
                                    o0.z + res[i][2], o0.w + res[i][3]);
        *(float4*)(dst + 4) = make_float4(o1.x + res[i][4], o1.y + res[i][5],
                                          o1.z + res[i][6], o1.w + res[i][7]);
    }
}

// ---------------------------------------------------------------------------
// launch
// ---------------------------------------------------------------------------
extern "C" void kernel_launch(void* const* d_in, const int* in_sizes, int n_in,
                              void* d_out, int out_size, void* d_ws, size_t ws_size,
                              hipStream_t stream)
{
    (void)in_sizes; (void)n_in; (void)out_size; (void)ws_size;
    const float* q  = (const float*)d_in[0];
    const float* k  = (const float*)d_in[1];
    const float* v  = (const float*)d_in[2];
    const float* cw = (const float*)d_in[3];
    float* out = (float*)d_out;
    float* ws  = (float*)d_ws;

    const size_t LM = (size_t)LM_E;   // 262144 floats
    const size_t MM = (size_t)MM_E;   // 1048576 floats

    // float-unit layout (total ~29.6 MB, <= proven 29.9 MB):
    float* ql  = ws;                  // LM
    float* kl  = ql  + LM;            // LM
    float* xsf = kl  + LM;            // MM floats  = xh|xl planes (2*MM ushorts)
    float* zsf = xsf + MM;            // MM floats  = zh|zl planes
    float* big = zsf + MM;            // 4*MM floats: pO (2*MM fl) then 8 planes
    float* kvf = big + 4 * MM;        // LM floats  = kvh|kvl planes
    float* W   = kvf + LM;            // LM floats
    float* scl = W   + LM;            // 16
    float* pm  = scl + 16;            // NBH*NSPLIT3*MLAND
    float* pl  = pm + (size_t)NBH * NSPLIT3 * MLAND;

    float* pO = big;                  // 2*MM floats, dead before pinv chain

    unsigned short* xs  = (unsigned short*)xsf;
    unsigned short* zs  = (unsigned short*)zsf;
    unsigned short* bgu = (unsigned short*)big;   // 8*MM ushorts
    unsigned short* kvs = (unsigned short*)kvf;

    unsigned short* xh  = xs;
    unsigned short* xl  = xs + MM;
    unsigned short* zh  = zs;
    unsigned short* zl  = zs + MM;
    unsigned short* z2h = bgu;
    unsigned short* z2l = bgu + MM;
    unsigned short* xzh = bgu + 2 * MM;
    unsigned short* xzl = bgu + 3 * MM;
    unsigned short* t2h = bgu + 4 * MM;
    unsigned short* t2l = bgu + 5 * MM;
    unsigned short* t3h = bgu + 6 * MM;
    unsigned short* t3l = bgu + 7 * MM;
    unsigned short* kvh = kvs;
    unsigned short* kvl = kvs + LM;

    hipMemsetAsync(scl, 0, 32, stream);

    k_landmarks<<<dim3(NBH * MLAND, 2), 64, 0, stream>>>(q, k, ql, kl);
    k_sim2_softmax<<<NBH * MLAND, 256, 0, stream>>>(ql, kl, xs);
    k_scale_reduce<<<dim3(16, NBH), 256, 0, stream>>>(xs, scl);
    k_zinit<<<dim3(8, 8, NBH), 256, 0, stream>>>(xs, zs, scl);

    k_attn3_partial<<<dim3(NSPLIT3, 4, NBH), 256, 0, stream>>>(ql, k, v, pO, pm, pl);
    k_attn3_combine<<<NBH * MLAND, 64, 0, stream>>>(pO, pm, pl, kvs);

    // Moore-Penrose: z' = 0.25*z@(13I - xz@(15I - xz@(7I - xz))), xz = x@z
    // 1-D grid 512: bh-pinned XCD swizzle (bh b on XCD b%8, all steps).
    unsigned short *zch = zh, *zcl = zl, *znh = z2h, *znl = z2l;
    for (int it = 0; it < 6; ++it) {
        k_bmm_planes<<<512, 256, 0, stream>>>(
            xh, xl, zch, zcl, xzh, xzl, nullptr, 256, 0.f, 1.f, 1.f);
        k_bmm_planes<<<512, 256, 0, stream>>>(
            xzh, xzl, xzh, xzl, t2h, t2l, nullptr, 256, 7.f, -1.f, 1.f);
        k_bmm_planes<<<512, 256, 0, stream>>>(
            xzh, xzl, t2h, t2l, t3h, t3l, nullptr, 256, 15.f, -1.f, 1.f);
        k_bmm_planes<<<512, 256, 0, stream>>>(
            zch, zcl, t3h, t3l, znh, znl, nullptr, 256, 13.f, -1.f, 0.25f);
        unsigned short* th = zch; zch = znh; znh = th;
        unsigned short* tl = zcl; zcl = znl; znl = tl;
    }
    // W = attn2_inv @ kv   [256x256 @ 256x64], fp32 out (grid 128, same swizzle)
    k_bmm_planes<<<128, 256, 0, stream>>>(
        zch, zcl, kvh, kvl, nullptr, nullptr, W, 64, 0.f, 1.f, 1.f);

    k_attn1_mfma<<<dim3(128, NBH), 256, 0, stream>>>(q, kl, W, out);
    k_conv_add<<<dim3(64, NBH), 256, 0, stream>>>(v, cw, out);
}